// Round 2
// baseline (755.594 us; speedup 1.0000x reference)
//
#include <hip/hip_runtime.h>
#include <hip/hip_bf16.h>

#define E_N 32768
#define H_N 256
#define S_N 32
#define NH_N 8
#define B_N 64
#define HD_N 32

// ---- workspace layout (float offsets) ----
#define OFF_QG     0                         // 32*256      = 8192
#define OFF_MT     16384                     // 512*256     = 131072
#define OFF_SEG    147456                    // 65 ints
#define OFF_SCORES 163840                    // E*256       = 8388608
#define OFF_V      (163840 + 8388608)        // E*256
#define OFF_ATT    (163840 + 2*8388608)      // 64*32*256   = 524288
#define OFF_GR     (OFF_ATT + 524288)        // 524288
#define OFF_PART   (OFF_GR + 524288)         // 8*64*256    = 131072
#define OFF_H1     (OFF_PART + 131072)       // 16384

// ---------------------------------------------------------------
// q[s][h] = sum_j seed[s][j] * Wq[h][j]       (grid 32 = s, block 256 = h)
__global__ __launch_bounds__(256) void proj_q(const float* __restrict__ seed,
                                              const float* __restrict__ Wq,
                                              float* __restrict__ q_g) {
    __shared__ float srow[256];
    const int s = blockIdx.x, h = threadIdx.x;
    srow[h] = seed[s * 256 + h];
    __syncthreads();
    const float4* wr = (const float4*)&Wq[h * 256];
    float acc = 0.f;
#pragma unroll 8
    for (int j4 = 0; j4 < 64; ++j4) {
        float4 w = wr[j4];
        acc += w.x * srow[j4 * 4 + 0] + w.y * srow[j4 * 4 + 1] +
               w.z * srow[j4 * 4 + 2] + w.w * srow[j4 * 4 + 3];
    }
    q_g[s * 256 + h] = acc;
}

// ---------------------------------------------------------------
// Build M^T [512 rows][256 k]:
//   rows c=nh*32+s   : Mt[c][k] = scale * sum_d Wk[nh*32+d][k] * q[s][nh*32+d]
//   rows 256+j       : Mt[256+j][k] = Wv[j][k]
// grid 16: blocks 0..7 -> QK part (nh = bid); blocks 8..15 -> Wv copy
__global__ __launch_bounds__(256) void build_M(const float* __restrict__ Wk,
                                               const float* __restrict__ Wv,
                                               const float* __restrict__ q_g,
                                               float* __restrict__ Mt) {
    const int tid = threadIdx.x;
    const int bid = blockIdx.x;
    if (bid < 8) {
        const int nh = bid;
        __shared__ float q_l[32][32];  // [s][d]
        for (int i = tid; i < 1024; i += 256) {
            int s = i >> 5, d = i & 31;
            q_l[s][d] = q_g[s * 256 + nh * 32 + d];
        }
        __syncthreads();
        float acc[32];
#pragma unroll
        for (int s = 0; s < 32; ++s) acc[s] = 0.f;
        for (int d = 0; d < 32; ++d) {
            float w = Wk[(nh * 32 + d) * 256 + tid];
#pragma unroll
            for (int s = 0; s < 32; ++s) acc[s] += w * q_l[s][d];
        }
        const float scale = 0.17677669529663687f;  // 1/sqrt(32)
        for (int s = 0; s < 32; ++s)
            Mt[(nh * 32 + s) * 256 + tid] = acc[s] * scale;
    } else {
        const int j0 = (bid - 8) * 32;
        for (int jj = 0; jj < 32; ++jj) {
            int j = j0 + jj;
            Mt[(256 + j) * 256 + tid] = Wv[j * 256 + tid];
        }
    }
}

// ---------------------------------------------------------------
// seg[b] = first index i with batch[i] >= b  (batch sorted); seg[64] = E
__global__ void seg_offsets(const int* __restrict__ batch, int* __restrict__ seg) {
    int b = threadIdx.x;
    if (b > 64) return;
    int lo = 0, hi = E_N;
    while (lo < hi) {
        int mid = (lo + hi) >> 1;
        if (batch[mid] < b) lo = mid + 1; else hi = mid;
    }
    seg[b] = lo;
}

// ---------------------------------------------------------------
// Generic C[r][c] = sum_k A[r][k]*W[c][k] (+bias[c]); K=256 fixed.
// cols c<256 -> out0[r*256+c], c>=256 -> out1[r*256+c-256]
// 64x64 tile, 256 threads, 4x4 per thread.
__global__ __launch_bounds__(256) void gemm_abT(const float* __restrict__ A,
                                                const float* __restrict__ W,
                                                const float* __restrict__ bias,
                                                float* __restrict__ out0,
                                                float* __restrict__ out1) {
    __shared__ float As[16][64];
    __shared__ float Bs[16][64];
    const int tid = threadIdx.x;
    const int m0 = blockIdx.y * 64, n0 = blockIdx.x * 64;
    const int tx = tid & 15, ty = tid >> 4;
    const int lrow = tid >> 2;       // 0..63
    const int lkq = (tid & 3) * 4;   // 0,4,8,12
    float acc[4][4];
#pragma unroll
    for (int i = 0; i < 4; ++i)
#pragma unroll
        for (int j = 0; j < 4; ++j) acc[i][j] = 0.f;

    for (int k0 = 0; k0 < 256; k0 += 16) {
        float4 av = *(const float4*)&A[(m0 + lrow) * 256 + k0 + lkq];
        float4 wv = *(const float4*)&W[(n0 + lrow) * 256 + k0 + lkq];
        As[lkq + 0][lrow] = av.x; As[lkq + 1][lrow] = av.y;
        As[lkq + 2][lrow] = av.z; As[lkq + 3][lrow] = av.w;
        Bs[lkq + 0][lrow] = wv.x; Bs[lkq + 1][lrow] = wv.y;
        Bs[lkq + 2][lrow] = wv.z; Bs[lkq + 3][lrow] = wv.w;
        __syncthreads();
#pragma unroll
        for (int k = 0; k < 16; ++k) {
            float4 a4 = *(const float4*)&As[k][ty * 4];
            float4 b4 = *(const float4*)&Bs[k][tx * 4];
            acc[0][0] += a4.x * b4.x; acc[0][1] += a4.x * b4.y;
            acc[0][2] += a4.x * b4.z; acc[0][3] += a4.x * b4.w;
            acc[1][0] += a4.y * b4.x; acc[1][1] += a4.y * b4.y;
            acc[1][2] += a4.y * b4.z; acc[1][3] += a4.y * b4.w;
            acc[2][0] += a4.z * b4.x; acc[2][1] += a4.z * b4.y;
            acc[2][2] += a4.z * b4.z; acc[2][3] += a4.z * b4.w;
            acc[3][0] += a4.w * b4.x; acc[3][1] += a4.w * b4.y;
            acc[3][2] += a4.w * b4.z; acc[3][3] += a4.w * b4.w;
        }
        __syncthreads();
    }

    const int c = n0 + tx * 4;
    float4 bb = bias ? *(const float4*)&bias[c] : make_float4(0.f, 0.f, 0.f, 0.f);
    const bool hi = (c >= 256);
    float* outp = hi ? out1 : out0;
    const int cc = hi ? c - 256 : c;
#pragma unroll
    for (int mi = 0; mi < 4; ++mi) {
        int r = m0 + ty * 4 + mi;
        float4 o = make_float4(acc[mi][0] + bb.x, acc[mi][1] + bb.y,
                               acc[mi][2] + bb.z, acc[mi][3] + bb.w);
        *(float4*)&outp[r * 256 + cc] = o;
    }
}

// ---------------------------------------------------------------
// Per-graph online softmax over edges + attended accumulation.
// grid B, block 256: thread t -> (nh=t>>5, s=t&31) == scores column t.
// Writes att[b][s][nh*32+hd]  (the [B,S,H] transposed layout directly).
__global__ __launch_bounds__(256) void seg_attend(const float* __restrict__ scores,
                                                  const float* __restrict__ v,
                                                  const int* __restrict__ seg,
                                                  float* __restrict__ att) {
    const int b = blockIdx.x;
    const int t = threadIdx.x;
    const int nh = t >> 5, s = t & 31;
    const int e0 = seg[b], e1 = seg[b + 1];

    float m = -3.4e38f, sum = 0.f;
    for (int e = e0; e < e1; ++e) {
        float x = scores[e * 256 + t];
        float nm = fmaxf(m, x);
        sum = sum * __expf(m - nm) + __expf(x - nm);
        m = nm;
    }
    float inv = (sum > 0.f) ? 1.f / sum : 0.f;

    float acc[32];
#pragma unroll
    for (int i = 0; i < 32; ++i) acc[i] = 0.f;
    for (int e = e0; e < e1; ++e) {
        float w = __expf(scores[e * 256 + t] - m) * inv;
        const float4* vr = (const float4*)&v[e * 256 + nh * 32];
#pragma unroll
        for (int i = 0; i < 8; ++i) {
            float4 vv = vr[i];
            acc[i * 4 + 0] += w * vv.x; acc[i * 4 + 1] += w * vv.y;
            acc[i * 4 + 2] += w * vv.z; acc[i * 4 + 3] += w * vv.w;
        }
    }
    float* op = &att[(b * 32 + s) * 256 + nh * 32];
#pragma unroll
    for (int i = 0; i < 8; ++i)
        ((float4*)op)[i] = make_float4(acc[i * 4 + 0], acc[i * 4 + 1],
                                       acc[i * 4 + 2], acc[i * 4 + 3]);
}

// ---------------------------------------------------------------
// W1 split-K: partials[ks][b][i] = sum_{k in slice ks} flat[b][k]*W1[i][k]
// grid (4 n-tiles, 8 k-splits); block 256; BM=64(all b), BN=64, slice=1024.
__global__ __launch_bounds__(256) void gemm_w1_splitk(const float* __restrict__ flat,
                                                      const float* __restrict__ W1,
                                                      float* __restrict__ partials) {
    __shared__ float As[16][64];  // [k][b]
    __shared__ float Bs[16][64];  // [k][i]
    const int tid = threadIdx.x;
    const int n0 = blockIdx.x * 64;
    const int kbase = blockIdx.y * 1024;
    const int tx = tid & 15, ty = tid >> 4;
    const int lrow = tid >> 2, lkq = (tid & 3) * 4;
    float acc[4][4];
#pragma unroll
    for (int i = 0; i < 4; ++i)
#pragma unroll
        for (int j = 0; j < 4; ++j) acc[i][j] = 0.f;

    for (int k0 = 0; k0 < 1024; k0 += 16) {
        float4 av = *(const float4*)&flat[lrow * 8192 + kbase + k0 + lkq];
        float4 wv = *(const float4*)&W1[(n0 + lrow) * 8192 + kbase + k0 + lkq];
        As[lkq + 0][lrow] = av.x; As[lkq + 1][lrow] = av.y;
        As[lkq + 2][lrow] = av.z; As[lkq + 3][lrow] = av.w;
        Bs[lkq + 0][lrow] = wv.x; Bs[lkq + 1][lrow] = wv.y;
        Bs[lkq + 2][lrow] = wv.z; Bs[lkq + 3][lrow] = wv.w;
        __syncthreads();
#pragma unroll
        for (int k = 0; k < 16; ++k) {
            float4 a4 = *(const float4*)&As[k][ty * 4];
            float4 b4 = *(const float4*)&Bs[k][tx * 4];
            acc[0][0] += a4.x * b4.x; acc[0][1] += a4.x * b4.y;
            acc[0][2] += a4.x * b4.z; acc[0][3] += a4.x * b4.w;
            acc[1][0] += a4.y * b4.x; acc[1][1] += a4.y * b4.y;
            acc[1][2] += a4.y * b4.z; acc[1][3] += a4.y * b4.w;
            acc[2][0] += a4.z * b4.x; acc[2][1] += a4.z * b4.y;
            acc[2][2] += a4.z * b4.z; acc[2][3] += a4.z * b4.w;
            acc[3][0] += a4.w * b4.x; acc[3][1] += a4.w * b4.y;
            acc[3][2] += a4.w * b4.z; acc[3][3] += a4.w * b4.w;
        }
        __syncthreads();
    }
#pragma unroll
    for (int mi = 0; mi < 4; ++mi) {
        int b = ty * 4 + mi;
        *(float4*)&partials[blockIdx.y * 16384 + b * 256 + n0 + tx * 4] =
            make_float4(acc[mi][0], acc[mi][1], acc[mi][2], acc[mi][3]);
    }
}

// ---------------------------------------------------------------
__global__ void silu_reduce(const float* __restrict__ partials,
                            const float* __restrict__ b1,
                            float* __restrict__ h1) {
    int t = blockIdx.x * 256 + threadIdx.x;  // 0..16383
    float sum = b1[t & 255];
    for (int ks = 0; ks < 8; ++ks) sum += partials[ks * 16384 + t];
    h1[t] = sum / (1.f + __expf(-sum));
}

// ---------------------------------------------------------------
extern "C" void kernel_launch(void* const* d_in, const int* in_sizes, int n_in,
                              void* d_out, int out_size, void* d_ws, size_t ws_size,
                              hipStream_t stream) {
    const float* X    = (const float*)d_in[0];
    const int*   batch = (const int*)d_in[2];
    const float* seed = (const float*)d_in[3];
    const float* Wq   = (const float*)d_in[4];
    const float* Wk   = (const float*)d_in[5];
    const float* Wv   = (const float*)d_in[6];
    const float* Wo   = (const float*)d_in[7];
    const float* bo   = (const float*)d_in[8];
    const float* W1   = (const float*)d_in[9];
    const float* b1   = (const float*)d_in[10];
    const float* W2   = (const float*)d_in[11];
    const float* b2   = (const float*)d_in[12];
    float* out = (float*)d_out;
    float* ws = (float*)d_ws;

    float* q_g    = ws + OFF_QG;
    float* Mt     = ws + OFF_MT;
    int*   seg    = (int*)(ws + OFF_SEG);
    float* scores = ws + OFF_SCORES;
    float* v      = ws + OFF_V;
    float* att    = ws + OFF_ATT;
    float* gr     = ws + OFF_GR;
    float* part   = ws + OFF_PART;
    float* h1     = ws + OFF_H1;

    hipLaunchKernelGGL(proj_q, dim3(32), dim3(256), 0, stream, seed, Wq, q_g);
    hipLaunchKernelGGL(build_M, dim3(16), dim3(256), 0, stream, Wk, Wv, q_g, Mt);
    hipLaunchKernelGGL(seg_offsets, dim3(1), dim3(128), 0, stream, batch, seg);
    // scores,v : [E,256] @ Mt^T  -> 8.6 GFLOP (dominant)
    hipLaunchKernelGGL(gemm_abT, dim3(8, 512), dim3(256), 0, stream,
                       X, Mt, (const float*)nullptr, scores, v);
    hipLaunchKernelGGL(seg_attend, dim3(64), dim3(256), 0, stream, scores, v, seg, att);
    // graph_repr = att @ Wo^T + bo   [2048,256]
    hipLaunchKernelGGL(gemm_abT, dim3(4, 32), dim3(256), 0, stream,
                       att, Wo, bo, gr, gr);
    // h1_pre split-K over K=8192
    hipLaunchKernelGGL(gemm_w1_splitk, dim3(4, 8), dim3(256), 0, stream, gr, W1, part);
    hipLaunchKernelGGL(silu_reduce, dim3(64), dim3(256), 0, stream, part, b1, h1);
    // out = h1 @ W2^T + b2   [64,256]
    hipLaunchKernelGGL(gemm_abT, dim3(4, 1), dim3(256), 0, stream,
                       h1, W2, b2, out, out);
}

// Round 5
// 313.932 us; speedup vs baseline: 2.4069x; 2.4069x over previous
//
#include <hip/hip_runtime.h>
#include <hip/hip_bf16.h>

#define E_N 32768
#define H_N 256
#define S_N 32
#define NH_N 8
#define B_N 64

typedef _Float16 f16x8 __attribute__((ext_vector_type(8)));
typedef _Float16 f16x4 __attribute__((ext_vector_type(4)));
typedef float    f32x4 __attribute__((ext_vector_type(4)));

// ---- workspace layout (float offsets) ----
#define OFF_MTH    0                  // 512*256 f16 = 65536 floats
#define OFF_MP     65536              // 64*8*256
#define OFF_SP     196608             // 64*8*256
#define OFF_MM     327680             // 64*256
#define OFF_DI     344064             // 64*256
#define OFF_ATT    360448             // 64*32*256
#define OFF_GR     884736             // 64*32*256
#define OFF_PART   1409024            // 8*64*256
#define OFF_H1     1540096            // 64*256
#define OFF_SCORES 1556480            // E*256 f32
#define OFF_VH     9945088            // E*256 f16 = 4194304 floats
// total 14139392 floats = 56.6 MB

__device__ inline int lower_bound64(const int* __restrict__ batch, int b) {
    int lo = 0, hi = E_N;
    while (lo < hi) { int mid = (lo + hi) >> 1; if (batch[mid] < b) lo = mid + 1; else hi = mid; }
    return lo;
}

// ---------------------------------------------------------------
// prep: blocks 0..7 compute q-head + Mth QK rows; blocks 8..15 copy Wv->f16.
// Mth row c=nh*32+s : scale * sum_d Wk[nh*32+d][k] * q[s][nh*32+d]
// Mth row 256+j     : Wv[j][k]
__global__ __launch_bounds__(256) void prep(const float* __restrict__ seed,
                                            const float* __restrict__ Wq,
                                            const float* __restrict__ Wk,
                                            const float* __restrict__ Wv,
                                            _Float16* __restrict__ Mth) {
    const int t = threadIdx.x, bid = blockIdx.x;
    if (bid < 8) {
        const int nh = bid;
        __shared__ float q_l[32][32];  // [s][d]
        const int d = t & 31, s0 = t >> 5;
        float a0 = 0, a1 = 0, a2 = 0, a3 = 0;
        const float* wq = &Wq[(nh * 32 + d) * 256];
        for (int j = 0; j < 256; ++j) {
            float w = wq[j];
            a0 += w * seed[(s0) * 256 + j];
            a1 += w * seed[(s0 + 8) * 256 + j];
            a2 += w * seed[(s0 + 16) * 256 + j];
            a3 += w * seed[(s0 + 24) * 256 + j];
        }
        q_l[s0][d] = a0; q_l[s0 + 8][d] = a1; q_l[s0 + 16][d] = a2; q_l[s0 + 24][d] = a3;
        __syncthreads();
        float acc[32];
#pragma unroll
        for (int s = 0; s < 32; ++s) acc[s] = 0.f;
        for (int dd = 0; dd < 32; ++dd) {
            float w = Wk[(nh * 32 + dd) * 256 + t];
#pragma unroll
            for (int s = 0; s < 32; ++s) acc[s] += w * q_l[s][dd];
        }
        const float scale = 0.17677669529663687f;  // 1/sqrt(32)
        for (int s = 0; s < 32; ++s)
            Mth[(nh * 32 + s) * 256 + t] = (_Float16)(acc[s] * scale);
    } else {
        const int j0 = (bid - 8) * 32;
        for (int jj = 0; jj < 32; ++jj)
            Mth[(256 + j0 + jj) * 256 + t] = (_Float16)Wv[(j0 + jj) * 256 + t];
    }
}

// ---------------------------------------------------------------
// f16 MFMA GEMM: C[r][c] = sum_k X[r][k]*Mth[c][k];  r<E, c<512.
// cols 0..255 -> scores (f32); cols 256..511 -> vh (f16).
// 128x128 tile, BK=64, 256 threads (4 waves, each 64x64 quadrant).
__global__ __launch_bounds__(256) void gemm16(const float* __restrict__ X,
                                              const _Float16* __restrict__ Mth,
                                              float* __restrict__ scores,
                                              _Float16* __restrict__ vh) {
    __shared__ _Float16 As[128][72];   // 144B row stride: 16B-aligned, ~uniform banks
    __shared__ _Float16 Bs[128][72];
    const int tid = threadIdx.x;
    const int n0 = blockIdx.x * 128;
    const int m0 = blockIdx.y * 128;
    const int w = tid >> 6, l = tid & 63;
    const int lr = l & 15, kg = l >> 4;
    const int wr = (w & 1) * 64, wc = (w >> 1) * 64;
    f32x4 acc[4][4] = {};

    for (int ks = 0; ks < 4; ++ks) {
        const int k0 = ks * 64;
        // stage A (f32 -> f16)
#pragma unroll
        for (int i = 0; i < 8; ++i) {
            int idx = tid + i * 256;          // 0..2047
            int row = idx >> 4, c4 = (idx & 15) * 4;
            float4 xv = *(const float4*)&X[(m0 + row) * 256 + k0 + c4];
            f16x4 h;
            h[0] = (_Float16)xv.x; h[1] = (_Float16)xv.y;
            h[2] = (_Float16)xv.z; h[3] = (_Float16)xv.w;
            *(f16x4*)&As[row][c4] = h;
        }
        // stage B (already f16)
#pragma unroll
        for (int i = 0; i < 4; ++i) {
            int idx = tid + i * 256;          // 0..1023
            int row = idx >> 3, c8 = (idx & 7) * 8;
            *(uint4*)&Bs[row][c8] = *(const uint4*)&Mth[(n0 + row) * 256 + k0 + c8];
        }
        __syncthreads();
#pragma unroll
        for (int kk = 0; kk < 2; ++kk) {
            f16x8 af[4], bf[4];
#pragma unroll
            for (int mr = 0; mr < 4; ++mr)
                af[mr] = *(const f16x8*)&As[wr + mr * 16 + lr][kk * 32 + kg * 8];
#pragma unroll
            for (int nc = 0; nc < 4; ++nc)
                bf[nc] = *(const f16x8*)&Bs[wc + nc * 16 + lr][kk * 32 + kg * 8];
#pragma unroll
            for (int mr = 0; mr < 4; ++mr)
#pragma unroll
                for (int nc = 0; nc < 4; ++nc)
                    acc[mr][nc] = __builtin_amdgcn_mfma_f32_16x16x32_f16(
                        af[mr], bf[nc], acc[mr][nc], 0, 0, 0);
        }
        __syncthreads();
    }
    // epilogue: D row = (lane>>4)*4 + j, col = lane&15 (m89-verified family)
    const int r0 = m0 + wr + kg * 4;
    if (n0 < 256) {
#pragma unroll
        for (int mr = 0; mr < 4; ++mr)
#pragma unroll
            for (int nc = 0; nc < 4; ++nc) {
                int col = n0 + wc + nc * 16 + lr;
#pragma unroll
                for (int j = 0; j < 4; ++j)
                    scores[(r0 + mr * 16 + j) * 256 + col] = acc[mr][nc][j];
            }
    } else {
#pragma unroll
        for (int mr = 0; mr < 4; ++mr)
#pragma unroll
            for (int nc = 0; nc < 4; ++nc) {
                int col = n0 - 256 + wc + nc * 16 + lr;
#pragma unroll
                for (int j = 0; j < 4; ++j)
                    vh[(r0 + mr * 16 + j) * 256 + col] = (_Float16)acc[mr][nc][j];
            }
    }
}

// ---------------------------------------------------------------
// stats_partial: grid (B, 8). Per (graph, chunk): per-column chunk max, then
// sum of exp(x - mloc). No loop-carried rescale -> loads pipeline freely.
__global__ __launch_bounds__(256) void stats_partial(const float* __restrict__ scores,
                                                     const int* __restrict__ batch,
                                                     float* __restrict__ mp,
                                                     float* __restrict__ sp) {
    const int b = blockIdx.x, c = blockIdx.y, t = threadIdx.x;
    const int e0 = lower_bound64(batch, b);
    const int e1 = lower_bound64(batch, b + 1);
    const int len = e1 - e0;
    const int cs = e0 + (len * c) / 8;
    const int ce = e0 + (len * (c + 1)) / 8;
    float m = -3.4e38f;
    for (int e = cs; e < ce; ++e) m = fmaxf(m, scores[e * 256 + t]);
    float s = 0.f;
    for (int e = cs; e < ce; ++e) s += __expf(scores[e * 256 + t] - m);
    mp[(b * 8 + c) * 256 + t] = m;
    sp[(b * 8 + c) * 256 + t] = s;
}

// ---------------------------------------------------------------
__global__ __launch_bounds__(256) void stats_merge(const float* __restrict__ mp,
                                                   const float* __restrict__ sp,
                                                   float* __restrict__ mm,
                                                   float* __restrict__ di) {
    const int b = blockIdx.x, t = threadIdx.x;
    float m = -3.4e38f;
#pragma unroll
    for (int c = 0; c < 8; ++c) m = fmaxf(m, mp[(b * 8 + c) * 256 + t]);
    float d = 0.f;
#pragma unroll
    for (int c = 0; c < 8; ++c) {
        float sc = sp[(b * 8 + c) * 256 + t];
        if (sc > 0.f) d += sc * __expf(mp[(b * 8 + c) * 256 + t] - m);
    }
    mm[b * 256 + t] = m;
    di[b * 256 + t] = (d > 0.f) ? 1.f / d : 0.f;
}

// ---------------------------------------------------------------
// attend: grid (B, NH). Per (graph, head): tile 32 edges x 32 cols through
// LDS, outer-product accumulate; writes att[b][s][nh*32+hd] (=[B,S,H]).
__global__ __launch_bounds__(256) void attend(const float* __restrict__ scores,
                                              const _Float16* __restrict__ vh,
                                              const int* __restrict__ batch,
                                              const float* __restrict__ mm,
                                              const float* __restrict__ di,
                                              float* __restrict__ att) {
    const int b = blockIdx.x, nh = blockIdx.y, t = threadIdx.x;
    const int e0 = lower_bound64(batch, b);
    const int e1 = lower_bound64(batch, b + 1);
    __shared__ float wl[32][33];
    __shared__ float vl[32][33];
    __shared__ float mc[32], dc[32];
    if (t < 32) {
        mc[t] = mm[b * 256 + nh * 32 + t];
        dc[t] = di[b * 256 + nh * 32 + t];
    }
    __syncthreads();
    const int s = t & 31, g = t >> 5;      // compute mapping
    const int le = t >> 3, q = t & 7;      // stage mapping
    float acc0 = 0.f, acc1 = 0.f, acc2 = 0.f, acc3 = 0.f;
    for (int te = e0; te < e1; te += 32) {
        const int e = te + le;
        const bool ok = (e < e1);
        float4 x = make_float4(0.f, 0.f, 0.f, 0.f);
        f16x4 vv = {};
        if (ok) {
            x = *(const float4*)&scores[e * 256 + nh * 32 + q * 4];
            vv = *(const f16x4*)&vh[e * 256 + nh * 32 + q * 4];
        }
        wl[le][q * 4 + 0] = ok ? __expf(x.x - mc[q * 4 + 0]) : 0.f;
        wl[le][q * 4 + 1] = ok ? __expf(x.y - mc[q * 4 + 1]) : 0.f;
        wl[le][q * 4 + 2] = ok ? __expf(x.z - mc[q * 4 + 2]) : 0.f;
        wl[le][q * 4 + 3] = ok ? __expf(x.w - mc[q * 4 + 3]) : 0.f;
        vl[le][q * 4 + 0] = ok ? (float)vv[0] : 0.f;
        vl[le][q * 4 + 1] = ok ? (float)vv[1] : 0.f;
        vl[le][q * 4 + 2] = ok ? (float)vv[2] : 0.f;
        vl[le][q * 4 + 3] = ok ? (float)vv[3] : 0.f;
        __syncthreads();
#pragma unroll
        for (int e2 = 0; e2 < 32; ++e2) {
            float wv = wl[e2][s];
            acc0 += wv * vl[e2][g * 4 + 0];
            acc1 += wv * vl[e2][g * 4 + 1];
            acc2 += wv * vl[e2][g * 4 + 2];
            acc3 += wv * vl[e2][g * 4 + 3];
        }
        __syncthreads();
    }
    const float dv = dc[s];
    float* op = &att[(b * 32 + s) * 256 + nh * 32 + g * 4];
    op[0] = acc0 * dv; op[1] = acc1 * dv; op[2] = acc2 * dv; op[3] = acc3 * dv;
}

// ---------------------------------------------------------------
// fp32 GEMM C[r][c] = sum_k A[r][k]*W[c][k] (+bias), K=256. (Wo / W2 — small)
__global__ __launch_bounds__(256) void gemm_abT(const float* __restrict__ A,
                                                const float* __restrict__ W,
                                                const float* __restrict__ bias,
                                                float* __restrict__ out0) {
    __shared__ float As[16][64];
    __shared__ float Bs[16][64];
    const int tid = threadIdx.x;
    const int m0 = blockIdx.y * 64, n0 = blockIdx.x * 64;
    const int tx = tid & 15, ty = tid >> 4;
    const int lrow = tid >> 2;
    const int lkq = (tid & 3) * 4;
    float acc[4][4];
#pragma unroll
    for (int i = 0; i < 4; ++i)
#pragma unroll
        for (int j = 0; j < 4; ++j) acc[i][j] = 0.f;

    for (int k0 = 0; k0 < 256; k0 += 16) {
        float4 av = *(const float4*)&A[(m0 + lrow) * 256 + k0 + lkq];
        float4 wv = *(const float4*)&W[(n0 + lrow) * 256 + k0 + lkq];
        As[lkq + 0][lrow] = av.x; As[lkq + 1][lrow] = av.y;
        As[lkq + 2][lrow] = av.z; As[lkq + 3][lrow] = av.w;
        Bs[lkq + 0][lrow] = wv.x; Bs[lkq + 1][lrow] = wv.y;
        Bs[lkq + 2][lrow] = wv.z; Bs[lkq + 3][lrow] = wv.w;
        __syncthreads();
#pragma unroll
        for (int k = 0; k < 16; ++k) {
            float4 a4 = *(const float4*)&As[k][ty * 4];
            float4 b4 = *(const float4*)&Bs[k][tx * 4];
            acc[0][0] += a4.x * b4.x; acc[0][1] += a4.x * b4.y;
            acc[0][2] += a4.x * b4.z; acc[0][3] += a4.x * b4.w;
            acc[1][0] += a4.y * b4.x; acc[1][1] += a4.y * b4.y;
            acc[1][2] += a4.y * b4.z; acc[1][3] += a4.y * b4.w;
            acc[2][0] += a4.z * b4.x; acc[2][1] += a4.z * b4.y;
            acc[2][2] += a4.z * b4.z; acc[2][3] += a4.z * b4.w;
            acc[3][0] += a4.w * b4.x; acc[3][1] += a4.w * b4.y;
            acc[3][2] += a4.w * b4.z; acc[3][3] += a4.w * b4.w;
        }
        __syncthreads();
    }
    const int c = n0 + tx * 4;
    float4 bb = bias ? *(const float4*)&bias[c]
                     : make_float4(0.f, 0.f, 0.f, 0.f);
#pragma unroll
    for (int mi = 0; mi < 4; ++mi) {
        int r = m0 + ty * 4 + mi;
        float4 o = make_float4(acc[mi][0] + bb.x, acc[mi][1] + bb.y,
                               acc[mi][2] + bb.z, acc[mi][3] + bb.w);
        *(float4*)&out0[r * 256 + c] = o;
    }
}

// ---------------------------------------------------------------
// W1 split-K: partials[ks][b][i] = sum_{k in slice} flat[b][k]*W1[i][k]
__global__ __launch_bounds__(256) void gemm_w1_splitk(const float* __restrict__ flat,
                                                      const float* __restrict__ W1,
                                                      float* __restrict__ partials) {
    __shared__ float As[16][64];
    __shared__ float Bs[16][64];
    const int tid = threadIdx.x;
    const int n0 = blockIdx.x * 64;
    const int kbase = blockIdx.y * 1024;
    const int tx = tid & 15, ty = tid >> 4;
    const int lrow = tid >> 2, lkq = (tid & 3) * 4;
    float acc[4][4];
#pragma unroll
    for (int i = 0; i < 4; ++i)
#pragma unroll
        for (int j = 0; j < 4; ++j) acc[i][j] = 0.f;

    for (int k0 = 0; k0 < 1024; k0 += 16) {
        float4 av = *(const float4*)&flat[lrow * 8192 + kbase + k0 + lkq];
        float4 wv = *(const float4*)&W1[(n0 + lrow) * 8192 + kbase + k0 + lkq];
        As[lkq + 0][lrow] = av.x; As[lkq + 1][lrow] = av.y;
        As[lkq + 2][lrow] = av.z; As[lkq + 3][lrow] = av.w;
        Bs[lkq + 0][lrow] = wv.x; Bs[lkq + 1][lrow] = wv.y;
        Bs[lkq + 2][lrow] = wv.z; Bs[lkq + 3][lrow] = wv.w;
        __syncthreads();
#pragma unroll
        for (int k = 0; k < 16; ++k) {
            float4 a4 = *(const float4*)&As[k][ty * 4];
            float4 b4 = *(const float4*)&Bs[k][tx * 4];
            acc[0][0] += a4.x * b4.x; acc[0][1] += a4.x * b4.y;
            acc[0][2] += a4.x * b4.z; acc[0][3] += a4.x * b4.w;
            acc[1][0] += a4.y * b4.x; acc[1][1] += a4.y * b4.y;
            acc[1][2] += a4.y * b4.z; acc[1][3] += a4.y * b4.w;
            acc[2][0] += a4.z * b4.x; acc[2][1] += a4.z * b4.y;
            acc[2][2] += a4.z * b4.z; acc[2][3] += a4.z * b4.w;
            acc[3][0] += a4.w * b4.x; acc[3][1] += a4.w * b4.y;
            acc[3][2] += a4.w * b4.z; acc[3][3] += a4.w * b4.w;
        }
        __syncthreads();
    }
#pragma unroll
    for (int mi = 0; mi < 4; ++mi) {
        int bb = ty * 4 + mi;
        *(float4*)&partials[blockIdx.y * 16384 + bb * 256 + n0 + tx * 4] =
            make_float4(acc[mi][0], acc[mi][1], acc[mi][2], acc[mi][3]);
    }
}

// ---------------------------------------------------------------
__global__ void silu_reduce(const float* __restrict__ partials,
                            const float* __restrict__ b1,
                            float* __restrict__ h1) {
    int t = blockIdx.x * 256 + threadIdx.x;  // 0..16383
    float sum = b1[t & 255];
    for (int ks = 0; ks < 8; ++ks) sum += partials[ks * 16384 + t];
    h1[t] = sum / (1.f + __expf(-sum));
}

// ---------------------------------------------------------------
extern "C" void kernel_launch(void* const* d_in, const int* in_sizes, int n_in,
                              void* d_out, int out_size, void* d_ws, size_t ws_size,
                              hipStream_t stream) {
    const float* X     = (const float*)d_in[0];
    const int*   batch = (const int*)d_in[2];
    const float* seed  = (const float*)d_in[3];
    const float* Wq    = (const float*)d_in[4];
    const float* Wk    = (const float*)d_in[5];
    const float* Wv    = (const float*)d_in[6];
    const float* Wo    = (const float*)d_in[7];
    const float* bo    = (const float*)d_in[8];
    const float* W1    = (const float*)d_in[9];
    const float* b1    = (const float*)d_in[10];
    const float* W2    = (const float*)d_in[11];
    const float* b2    = (const float*)d_in[12];
    float* out = (float*)d_out;
    float* ws = (float*)d_ws;

    _Float16* Mth   = (_Float16*)(ws + OFF_MTH);
    float* mp       = ws + OFF_MP;
    float* sp       = ws + OFF_SP;
    float* mm       = ws + OFF_MM;
    float* di       = ws + OFF_DI;
    float* att      = ws + OFF_ATT;
    float* gr       = ws + OFF_GR;
    float* part     = ws + OFF_PART;
    float* h1       = ws + OFF_H1;
    float* scores   = ws + OFF_SCORES;
    _Float16* vh    = (_Float16*)(ws + OFF_VH);

    hipLaunchKernelGGL(prep, dim3(16), dim3(256), 0, stream, seed, Wq, Wk, Wv, Mth);
    // scores (f32) + v (f16): [E,256]@[256,512] via f16 MFMA
    hipLaunchKernelGGL(gemm16, dim3(4, 256), dim3(256), 0, stream, X, Mth, scores, vh);
    hipLaunchKernelGGL(stats_partial, dim3(64, 8), dim3(256), 0, stream, scores, batch, mp, sp);
    hipLaunchKernelGGL(stats_merge, dim3(64), dim3(256), 0, stream, mp, sp, mm, di);
    hipLaunchKernelGGL(attend, dim3(64, 8), dim3(256), 0, stream, scores, vh, batch, mm, di, att);
    // graph_repr = att @ Wo^T + bo   [2048,256]
    hipLaunchKernelGGL(gemm_abT, dim3(4, 32), dim3(256), 0, stream, att, Wo, bo, gr);
    // h1_pre split-K over K=8192
    hipLaunchKernelGGL(gemm_w1_splitk, dim3(4, 8), dim3(256), 0, stream, gr, W1, part);
    hipLaunchKernelGGL(silu_reduce, dim3(64), dim3(256), 0, stream, part, b1, h1);
    // out = h1 @ W2^T + b2   [64,256]
    hipLaunchKernelGGL(gemm_abT, dim3(4, 1), dim3(256), 0, stream, h1, W2, b2, out);
}

// Round 6
// 273.930 us; speedup vs baseline: 2.7584x; 1.1460x over previous
//
#include <hip/hip_runtime.h>
#include <hip/hip_bf16.h>

#define E_N 32768
#define H_N 256
#define S_N 32
#define NH_N 8
#define B_N 64

typedef _Float16 f16x8 __attribute__((ext_vector_type(8)));
typedef _Float16 f16x4 __attribute__((ext_vector_type(4)));
typedef float    f32x4 __attribute__((ext_vector_type(4)));

// ---- workspace layout (float offsets) ----
#define OFF_MTH    0                  // 512*256 f16 = 65536 floats
#define OFF_MP     65536              // 64*8*256
#define OFF_SP     196608             // 64*8*256
#define OFF_MM     327680             // 64*256
#define OFF_DI     344064             // 64*256
#define OFF_ATT    360448             // 64*32*256
#define OFF_GR     884736             // 64*32*256
#define OFF_PART   1409024            // 64*64*256 = 1048576 (64 k-splits)
#define OFF_H1     2457600            // 64*256
#define OFF_SCORES 2473984            // E*256 f32
#define OFF_VH     10862592           // E*256 f16 = 4194304 floats
// total 15056896 floats = 60.2 MB (ws >= ~70MB proven in round 2)

__device__ inline int lower_bound64(const int* __restrict__ batch, int b) {
    int lo = 0, hi = E_N;
    while (lo < hi) { int mid = (lo + hi) >> 1; if (batch[mid] < b) lo = mid + 1; else hi = mid; }
    return lo;
}

// ---------------------------------------------------------------
// prep: blocks 0..7 compute q-head + Mth QK rows; blocks 8..15 copy Wv->f16.
__global__ __launch_bounds__(256) void prep(const float* __restrict__ seed,
                                            const float* __restrict__ Wq,
                                            const float* __restrict__ Wk,
                                            const float* __restrict__ Wv,
                                            _Float16* __restrict__ Mth) {
    const int t = threadIdx.x, bid = blockIdx.x;
    if (bid < 8) {
        const int nh = bid;
        __shared__ float q_l[32][32];  // [s][d]
        const int d = t & 31, s0 = t >> 5;
        float a0 = 0, a1 = 0, a2 = 0, a3 = 0;
        const float* wq = &Wq[(nh * 32 + d) * 256];
        for (int j = 0; j < 256; ++j) {
            float w = wq[j];
            a0 += w * seed[(s0) * 256 + j];
            a1 += w * seed[(s0 + 8) * 256 + j];
            a2 += w * seed[(s0 + 16) * 256 + j];
            a3 += w * seed[(s0 + 24) * 256 + j];
        }
        q_l[s0][d] = a0; q_l[s0 + 8][d] = a1; q_l[s0 + 16][d] = a2; q_l[s0 + 24][d] = a3;
        __syncthreads();
        float acc[32];
#pragma unroll
        for (int s = 0; s < 32; ++s) acc[s] = 0.f;
        for (int dd = 0; dd < 32; ++dd) {
            float w = Wk[(nh * 32 + dd) * 256 + t];
#pragma unroll
            for (int s = 0; s < 32; ++s) acc[s] += w * q_l[s][dd];
        }
        const float scale = 0.17677669529663687f;  // 1/sqrt(32)
        for (int s = 0; s < 32; ++s)
            Mth[(nh * 32 + s) * 256 + t] = (_Float16)(acc[s] * scale);
    } else {
        const int j0 = (bid - 8) * 32;
        for (int jj = 0; jj < 32; ++jj)
            Mth[(256 + j0 + jj) * 256 + t] = (_Float16)Wv[(j0 + jj) * 256 + t];
    }
}

// ---------------------------------------------------------------
// f16 MFMA GEMM: C[r][c] = sum_k X[r][k]*Mth[c][k];  r<E, c<512.
// cols 0..255 -> scores (f32); cols 256..511 -> vh (f16).
__global__ __launch_bounds__(256) void gemm16(const float* __restrict__ X,
                                              const _Float16* __restrict__ Mth,
                                              float* __restrict__ scores,
                                              _Float16* __restrict__ vh) {
    __shared__ _Float16 As[128][72];   // 144B row stride: 16B-aligned, ~uniform banks
    __shared__ _Float16 Bs[128][72];
    const int tid = threadIdx.x;
    const int n0 = blockIdx.x * 128;
    const int m0 = blockIdx.y * 128;
    const int w = tid >> 6, l = tid & 63;
    const int lr = l & 15, kg = l >> 4;
    const int wr = (w & 1) * 64, wc = (w >> 1) * 64;
    f32x4 acc[4][4] = {};

    for (int ks = 0; ks < 4; ++ks) {
        const int k0 = ks * 64;
        // stage A (f32 -> f16)
#pragma unroll
        for (int i = 0; i < 8; ++i) {
            int idx = tid + i * 256;          // 0..2047
            int row = idx >> 4, c4 = (idx & 15) * 4;
            float4 xv = *(const float4*)&X[(m0 + row) * 256 + k0 + c4];
            f16x4 h;
            h[0] = (_Float16)xv.x; h[1] = (_Float16)xv.y;
            h[2] = (_Float16)xv.z; h[3] = (_Float16)xv.w;
            *(f16x4*)&As[row][c4] = h;
        }
        // stage B (already f16)
#pragma unroll
        for (int i = 0; i < 4; ++i) {
            int idx = tid + i * 256;          // 0..1023
            int row = idx >> 3, c8 = (idx & 7) * 8;
            *(uint4*)&Bs[row][c8] = *(const uint4*)&Mth[(n0 + row) * 256 + k0 + c8];
        }
        __syncthreads();
#pragma unroll
        for (int kk = 0; kk < 2; ++kk) {
            f16x8 af[4], bf[4];
#pragma unroll
            for (int mr = 0; mr < 4; ++mr)
                af[mr] = *(const f16x8*)&As[wr + mr * 16 + lr][kk * 32 + kg * 8];
#pragma unroll
            for (int nc = 0; nc < 4; ++nc)
                bf[nc] = *(const f16x8*)&Bs[wc + nc * 16 + lr][kk * 32 + kg * 8];
#pragma unroll
            for (int mr = 0; mr < 4; ++mr)
#pragma unroll
                for (int nc = 0; nc < 4; ++nc)
                    acc[mr][nc] = __builtin_amdgcn_mfma_f32_16x16x32_f16(
                        af[mr], bf[nc], acc[mr][nc], 0, 0, 0);
        }
        __syncthreads();
    }
    // epilogue: D row = (lane>>4)*4 + j, col = lane&15
    const int r0 = m0 + wr + kg * 4;
    if (n0 < 256) {
#pragma unroll
        for (int mr = 0; mr < 4; ++mr)
#pragma unroll
            for (int nc = 0; nc < 4; ++nc) {
                int col = n0 + wc + nc * 16 + lr;
#pragma unroll
                for (int j = 0; j < 4; ++j)
                    scores[(r0 + mr * 16 + j) * 256 + col] = acc[mr][nc][j];
            }
    } else {
#pragma unroll
        for (int mr = 0; mr < 4; ++mr)
#pragma unroll
            for (int nc = 0; nc < 4; ++nc) {
                int col = n0 - 256 + wc + nc * 16 + lr;
#pragma unroll
                for (int j = 0; j < 4; ++j)
                    vh[(r0 + mr * 16 + j) * 256 + col] = (_Float16)acc[mr][nc][j];
            }
    }
}

// ---------------------------------------------------------------
// stats_partial: grid (B, 8). Per (graph, chunk): per-column chunk max, then
// sum of exp(x - mloc).
__global__ __launch_bounds__(256) void stats_partial(const float* __restrict__ scores,
                                                     const int* __restrict__ batch,
                                                     float* __restrict__ mp,
                                                     float* __restrict__ sp) {
    const int b = blockIdx.x, c = blockIdx.y, t = threadIdx.x;
    const int e0 = lower_bound64(batch, b);
    const int e1 = lower_bound64(batch, b + 1);
    const int len = e1 - e0;
    const int cs = e0 + (len * c) / 8;
    const int ce = e0 + (len * (c + 1)) / 8;
    float m = -3.4e38f;
    for (int e = cs; e < ce; ++e) m = fmaxf(m, scores[e * 256 + t]);
    float s = 0.f;
    for (int e = cs; e < ce; ++e) s += __expf(scores[e * 256 + t] - m);
    mp[(b * 8 + c) * 256 + t] = m;
    sp[(b * 8 + c) * 256 + t] = s;
}

// ---------------------------------------------------------------
__global__ __launch_bounds__(256) void stats_merge(const float* __restrict__ mp,
                                                   const float* __restrict__ sp,
                                                   float* __restrict__ mm,
                                                   float* __restrict__ di) {
    const int b = blockIdx.x, t = threadIdx.x;
    float m = -3.4e38f;
#pragma unroll
    for (int c = 0; c < 8; ++c) m = fmaxf(m, mp[(b * 8 + c) * 256 + t]);
    float d = 0.f;
#pragma unroll
    for (int c = 0; c < 8; ++c) {
        float sc = sp[(b * 8 + c) * 256 + t];
        if (sc > 0.f) d += sc * __expf(mp[(b * 8 + c) * 256 + t] - m);
    }
    mm[b * 256 + t] = m;
    di[b * 256 + t] = (d > 0.f) ? 1.f / d : 0.f;
}

// ---------------------------------------------------------------
// attend: grid (B, NH). Per (graph, head): tile 32 edges x 32 cols through
// LDS, outer-product accumulate; writes att[b][s][nh*32+hd] (=[B,S,H]).
__global__ __launch_bounds__(256) void attend(const float* __restrict__ scores,
                                              const _Float16* __restrict__ vh,
                                              const int* __restrict__ batch,
                                              const float* __restrict__ mm,
                                              const float* __restrict__ di,
                                              float* __restrict__ att) {
    const int b = blockIdx.x, nh = blockIdx.y, t = threadIdx.x;
    const int e0 = lower_bound64(batch, b);
    const int e1 = lower_bound64(batch, b + 1);
    __shared__ float wl[32][33];
    __shared__ float vl[32][33];
    __shared__ float mc[32], dc[32];
    if (t < 32) {
        mc[t] = mm[b * 256 + nh * 32 + t];
        dc[t] = di[b * 256 + nh * 32 + t];
    }
    __syncthreads();
    const int s = t & 31, g = t >> 5;      // compute mapping
    const int le = t >> 3, q = t & 7;      // stage mapping
    float acc0 = 0.f, acc1 = 0.f, acc2 = 0.f, acc3 = 0.f;
    for (int te = e0; te < e1; te += 32) {
        const int e = te + le;
        const bool ok = (e < e1);
        float4 x = make_float4(0.f, 0.f, 0.f, 0.f);
        f16x4 vv = {};
        if (ok) {
            x = *(const float4*)&scores[e * 256 + nh * 32 + q * 4];
            vv = *(const f16x4*)&vh[e * 256 + nh * 32 + q * 4];
        }
        wl[le][q * 4 + 0] = ok ? __expf(x.x - mc[q * 4 + 0]) : 0.f;
        wl[le][q * 4 + 1] = ok ? __expf(x.y - mc[q * 4 + 1]) : 0.f;
        wl[le][q * 4 + 2] = ok ? __expf(x.z - mc[q * 4 + 2]) : 0.f;
        wl[le][q * 4 + 3] = ok ? __expf(x.w - mc[q * 4 + 3]) : 0.f;
        vl[le][q * 4 + 0] = ok ? (float)vv[0] : 0.f;
        vl[le][q * 4 + 1] = ok ? (float)vv[1] : 0.f;
        vl[le][q * 4 + 2] = ok ? (float)vv[2] : 0.f;
        vl[le][q * 4 + 3] = ok ? (float)vv[3] : 0.f;
        __syncthreads();
#pragma unroll
        for (int e2 = 0; e2 < 32; ++e2) {
            float wv = wl[e2][s];
            acc0 += wv * vl[e2][g * 4 + 0];
            acc1 += wv * vl[e2][g * 4 + 1];
            acc2 += wv * vl[e2][g * 4 + 2];
            acc3 += wv * vl[e2][g * 4 + 3];
        }
        __syncthreads();
    }
    const float dv = dc[s];
    float* op = &att[(b * 32 + s) * 256 + nh * 32 + g * 4];
    op[0] = acc0 * dv; op[1] = acc1 * dv; op[2] = acc2 * dv; op[3] = acc3 * dv;
}

// ---------------------------------------------------------------
// fp32 GEMM C[r][c] = sum_k A[r][k]*W[c][k] (+bias), K=256. (Wo / W2 — small)
__global__ __launch_bounds__(256) void gemm_abT(const float* __restrict__ A,
                                                const float* __restrict__ W,
                                                const float* __restrict__ bias,
                                                float* __restrict__ out0) {
    __shared__ float As[16][64];
    __shared__ float Bs[16][64];
    const int tid = threadIdx.x;
    const int m0 = blockIdx.y * 64, n0 = blockIdx.x * 64;
    const int tx = tid & 15, ty = tid >> 4;
    const int lrow = tid >> 2;
    const int lkq = (tid & 3) * 4;
    float acc[4][4];
#pragma unroll
    for (int i = 0; i < 4; ++i)
#pragma unroll
        for (int j = 0; j < 4; ++j) acc[i][j] = 0.f;

    for (int k0 = 0; k0 < 256; k0 += 16) {
        float4 av = *(const float4*)&A[(m0 + lrow) * 256 + k0 + lkq];
        float4 wv = *(const float4*)&W[(n0 + lrow) * 256 + k0 + lkq];
        As[lkq + 0][lrow] = av.x; As[lkq + 1][lrow] = av.y;
        As[lkq + 2][lrow] = av.z; As[lkq + 3][lrow] = av.w;
        Bs[lkq + 0][lrow] = wv.x; Bs[lkq + 1][lrow] = wv.y;
        Bs[lkq + 2][lrow] = wv.z; Bs[lkq + 3][lrow] = wv.w;
        __syncthreads();
#pragma unroll
        for (int k = 0; k < 16; ++k) {
            float4 a4 = *(const float4*)&As[k][ty * 4];
            float4 b4 = *(const float4*)&Bs[k][tx * 4];
            acc[0][0] += a4.x * b4.x; acc[0][1] += a4.x * b4.y;
            acc[0][2] += a4.x * b4.z; acc[0][3] += a4.x * b4.w;
            acc[1][0] += a4.y * b4.x; acc[1][1] += a4.y * b4.y;
            acc[1][2] += a4.y * b4.z; acc[1][3] += a4.y * b4.w;
            acc[2][0] += a4.z * b4.x; acc[2][1] += a4.z * b4.y;
            acc[2][2] += a4.z * b4.z; acc[2][3] += a4.z * b4.w;
            acc[3][0] += a4.w * b4.x; acc[3][1] += a4.w * b4.y;
            acc[3][2] += a4.w * b4.z; acc[3][3] += a4.w * b4.w;
        }
        __syncthreads();
    }
    const int c = n0 + tx * 4;
    float4 bb = bias ? *(const float4*)&bias[c]
                     : make_float4(0.f, 0.f, 0.f, 0.f);
#pragma unroll
    for (int mi = 0; mi < 4; ++mi) {
        int r = m0 + ty * 4 + mi;
        float4 o = make_float4(acc[mi][0] + bb.x, acc[mi][1] + bb.y,
                               acc[mi][2] + bb.z, acc[mi][3] + bb.w);
        *(float4*)&out0[r * 256 + c] = o;
    }
}

// ---------------------------------------------------------------
// W1 split-K: 64 k-splits of 128. grid (4 n-tiles, 64 k-splits) = 256 blocks.
// R5 fix: was (4,8)=32 blocks -> 1.3% occupancy, 136 GB/s, latency-bound 64us.
// partials[ks][b][i] = sum_{k in slice ks} flat[b][k]*W1[i][k]
__global__ __launch_bounds__(256) void gemm_w1_splitk(const float* __restrict__ flat,
                                                      const float* __restrict__ W1,
                                                      float* __restrict__ partials) {
    __shared__ float As[16][64];
    __shared__ float Bs[16][64];
    const int tid = threadIdx.x;
    const int n0 = blockIdx.x * 64;
    const int kbase = blockIdx.y * 128;
    const int tx = tid & 15, ty = tid >> 4;
    const int lrow = tid >> 2, lkq = (tid & 3) * 4;
    float acc[4][4];
#pragma unroll
    for (int i = 0; i < 4; ++i)
#pragma unroll
        for (int j = 0; j < 4; ++j) acc[i][j] = 0.f;

    for (int k0 = 0; k0 < 128; k0 += 16) {
        float4 av = *(const float4*)&flat[lrow * 8192 + kbase + k0 + lkq];
        float4 wv = *(const float4*)&W1[(n0 + lrow) * 8192 + kbase + k0 + lkq];
        As[lkq + 0][lrow] = av.x; As[lkq + 1][lrow] = av.y;
        As[lkq + 2][lrow] = av.z; As[lkq + 3][lrow] = av.w;
        Bs[lkq + 0][lrow] = wv.x; Bs[lkq + 1][lrow] = wv.y;
        Bs[lkq + 2][lrow] = wv.z; Bs[lkq + 3][lrow] = wv.w;
        __syncthreads();
#pragma unroll
        for (int k = 0; k < 16; ++k) {
            float4 a4 = *(const float4*)&As[k][ty * 4];
            float4 b4 = *(const float4*)&Bs[k][tx * 4];
            acc[0][0] += a4.x * b4.x; acc[0][1] += a4.x * b4.y;
            acc[0][2] += a4.x * b4.z; acc[0][3] += a4.x * b4.w;
            acc[1][0] += a4.y * b4.x; acc[1][1] += a4.y * b4.y;
            acc[1][2] += a4.y * b4.z; acc[1][3] += a4.y * b4.w;
            acc[2][0] += a4.z * b4.x; acc[2][1] += a4.z * b4.y;
            acc[2][2] += a4.z * b4.z; acc[2][3] += a4.z * b4.w;
            acc[3][0] += a4.w * b4.x; acc[3][1] += a4.w * b4.y;
            acc[3][2] += a4.w * b4.z; acc[3][3] += a4.w * b4.w;
        }
        __syncthreads();
    }
#pragma unroll
    for (int mi = 0; mi < 4; ++mi) {
        int bb = ty * 4 + mi;
        *(float4*)&partials[blockIdx.y * 16384 + bb * 256 + n0 + tx * 4] =
            make_float4(acc[mi][0], acc[mi][1], acc[mi][2], acc[mi][3]);
    }
}

// ---------------------------------------------------------------
__global__ void silu_reduce(const float* __restrict__ partials,
                            const float* __restrict__ b1,
                            float* __restrict__ h1) {
    int t = blockIdx.x * 256 + threadIdx.x;  // 0..16383
    float sum = b1[t & 255];
    for (int ks = 0; ks < 64; ++ks) sum += partials[ks * 16384 + t];
    h1[t] = sum / (1.f + __expf(-sum));
}

// ---------------------------------------------------------------
extern "C" void kernel_launch(void* const* d_in, const int* in_sizes, int n_in,
                              void* d_out, int out_size, void* d_ws, size_t ws_size,
                              hipStream_t stream) {
    const float* X     = (const float*)d_in[0];
    const int*   batch = (const int*)d_in[2];
    const float* seed  = (const float*)d_in[3];
    const float* Wq    = (const float*)d_in[4];
    const float* Wk    = (const float*)d_in[5];
    const float* Wv    = (const float*)d_in[6];
    const float* Wo    = (const float*)d_in[7];
    const float* bo    = (const float*)d_in[8];
    const float* W1    = (const float*)d_in[9];
    const float* b1    = (const float*)d_in[10];
    const float* W2    = (const float*)d_in[11];
    const float* b2    = (const float*)d_in[12];
    float* out = (float*)d_out;
    float* ws = (float*)d_ws;

    _Float16* Mth   = (_Float16*)(ws + OFF_MTH);
    float* mp       = ws + OFF_MP;
    float* sp       = ws + OFF_SP;
    float* mm       = ws + OFF_MM;
    float* di       = ws + OFF_DI;
    float* att      = ws + OFF_ATT;
    float* gr       = ws + OFF_GR;
    float* part     = ws + OFF_PART;
    float* h1       = ws + OFF_H1;
    float* scores   = ws + OFF_SCORES;
    _Float16* vh    = (_Float16*)(ws + OFF_VH);

    hipLaunchKernelGGL(prep, dim3(16), dim3(256), 0, stream, seed, Wq, Wk, Wv, Mth);
    // scores (f32) + v (f16): [E,256]@[256,512] via f16 MFMA
    hipLaunchKernelGGL(gemm16, dim3(4, 256), dim3(256), 0, stream, X, Mth, scores, vh);
    hipLaunchKernelGGL(stats_partial, dim3(64, 8), dim3(256), 0, stream, scores, batch, mp, sp);
    hipLaunchKernelGGL(stats_merge, dim3(64), dim3(256), 0, stream, mp, sp, mm, di);
    hipLaunchKernelGGL(attend, dim3(64, 8), dim3(256), 0, stream, scores, vh, batch, mm, di, att);
    // graph_repr = att @ Wo^T + bo   [2048,256]
    hipLaunchKernelGGL(gemm_abT, dim3(4, 32), dim3(256), 0, stream, att, Wo, bo, gr);
    // h1_pre split-K over K=8192, 64-way split (256 blocks)
    hipLaunchKernelGGL(gemm_w1_splitk, dim3(4, 64), dim3(256), 0, stream, gr, W1, part);
    hipLaunchKernelGGL(silu_reduce, dim3(64), dim3(256), 0, stream, part, b1, h1);
    // out = h1 @ W2^T + b2   [64,256]
    hipLaunchKernelGGL(gemm_abT, dim3(4, 1), dim3(256), 0, stream, h1, W2, b2, out);
}

// Round 7
// 247.512 us; speedup vs baseline: 3.0528x; 1.1067x over previous
//
#include <hip/hip_runtime.h>
#include <hip/hip_bf16.h>

#define E_N 32768
#define H_N 256
#define S_N 32
#define NH_N 8
#define B_N 64

typedef _Float16 f16x8 __attribute__((ext_vector_type(8)));
typedef _Float16 f16x4 __attribute__((ext_vector_type(4)));
typedef float    f32x4 __attribute__((ext_vector_type(4)));

// ---- workspace layout (float offsets) ----
// [MTH][MM][DI][ MP | SP  (overlaid later by ATT4) ][ATT][GR][PART][H1][SCORES][VH]
#define OFF_MTH    0                  // 512*256 f16 = 65536 floats
#define OFF_MM     65536              // 64*256
#define OFF_DI     81920              // 64*256
#define OFF_MP     98304              // 64*32*256 = 524288
#define OFF_SP     622592             // 64*32*256 = 524288
#define OFF_ATT4   98304              // 4*2048*256 = 2097152 (overlays MP/SP after merge)
#define OFF_ATT    2195456            // 2048*256 = 524288
#define OFF_GR     2719744            // 524288
#define OFF_PART   3244032            // 64*16384 = 1048576
#define OFF_H1     4292608            // 16384
#define OFF_SCORES 4308992            // E*256 f32 = 8388608
#define OFF_VH     12697600           // E*256 f16 = 4194304 floats
// total 16891904 floats = 67.6 MB (72.3 MB proven OK in round 0)

__device__ inline int lower_bound64(const int* __restrict__ batch, int b) {
    int lo = 0, hi = E_N;
    while (lo < hi) { int mid = (lo + hi) >> 1; if (batch[mid] < b) lo = mid + 1; else hi = mid; }
    return lo;
}

// ---------------------------------------------------------------
// prep: blocks 0..7 compute q-head + Mth QK rows; blocks 8..15 copy Wv->f16.
__global__ __launch_bounds__(256) void prep(const float* __restrict__ seed,
                                            const float* __restrict__ Wq,
                                            const float* __restrict__ Wk,
                                            const float* __restrict__ Wv,
                                            _Float16* __restrict__ Mth) {
    const int t = threadIdx.x, bid = blockIdx.x;
    if (bid < 8) {
        const int nh = bid;
        __shared__ float q_l[32][32];  // [s][d]
        const int d = t & 31, s0 = t >> 5;
        float a0 = 0, a1 = 0, a2 = 0, a3 = 0;
        const float* wq = &Wq[(nh * 32 + d) * 256];
        for (int j = 0; j < 256; ++j) {
            float w = wq[j];
            a0 += w * seed[(s0) * 256 + j];
            a1 += w * seed[(s0 + 8) * 256 + j];
            a2 += w * seed[(s0 + 16) * 256 + j];
            a3 += w * seed[(s0 + 24) * 256 + j];
        }
        q_l[s0][d] = a0; q_l[s0 + 8][d] = a1; q_l[s0 + 16][d] = a2; q_l[s0 + 24][d] = a3;
        __syncthreads();
        float acc[32];
#pragma unroll
        for (int s = 0; s < 32; ++s) acc[s] = 0.f;
        for (int dd = 0; dd < 32; ++dd) {
            float w = Wk[(nh * 32 + dd) * 256 + t];
#pragma unroll
            for (int s = 0; s < 32; ++s) acc[s] += w * q_l[s][dd];
        }
        const float scale = 0.17677669529663687f;  // 1/sqrt(32)
        for (int s = 0; s < 32; ++s)
            Mth[(nh * 32 + s) * 256 + t] = (_Float16)(acc[s] * scale);
    } else {
        const int j0 = (bid - 8) * 32;
        for (int jj = 0; jj < 32; ++jj)
            Mth[(256 + j0 + jj) * 256 + t] = (_Float16)Wv[(j0 + jj) * 256 + t];
    }
}

// ---------------------------------------------------------------
// f16 MFMA GEMM: C[r][c] = sum_k X[r][k]*Mth[c][k];  r<E, c<512.
// cols 0..255 -> scores (f32); cols 256..511 -> vh (f16).
__global__ __launch_bounds__(256) void gemm16(const float* __restrict__ X,
                                              const _Float16* __restrict__ Mth,
                                              float* __restrict__ scores,
                                              _Float16* __restrict__ vh) {
    __shared__ _Float16 As[128][72];   // 144B row stride
    __shared__ _Float16 Bs[128][72];
    const int tid = threadIdx.x;
    const int n0 = blockIdx.x * 128;
    const int m0 = blockIdx.y * 128;
    const int w = tid >> 6, l = tid & 63;
    const int lr = l & 15, kg = l >> 4;
    const int wr = (w & 1) * 64, wc = (w >> 1) * 64;
    f32x4 acc[4][4] = {};

    for (int ks = 0; ks < 4; ++ks) {
        const int k0 = ks * 64;
        // stage A (f32 -> f16)
#pragma unroll
        for (int i = 0; i < 8; ++i) {
            int idx = tid + i * 256;          // 0..2047
            int row = idx >> 4, c4 = (idx & 15) * 4;
            float4 xv = *(const float4*)&X[(m0 + row) * 256 + k0 + c4];
            f16x4 h;
            h[0] = (_Float16)xv.x; h[1] = (_Float16)xv.y;
            h[2] = (_Float16)xv.z; h[3] = (_Float16)xv.w;
            *(f16x4*)&As[row][c4] = h;
        }
        // stage B (already f16)
#pragma unroll
        for (int i = 0; i < 4; ++i) {
            int idx = tid + i * 256;          // 0..1023
            int row = idx >> 3, c8 = (idx & 7) * 8;
            *(uint4*)&Bs[row][c8] = *(const uint4*)&Mth[(n0 + row) * 256 + k0 + c8];
        }
        __syncthreads();
#pragma unroll
        for (int kk = 0; kk < 2; ++kk) {
            f16x8 af[4], bf[4];
#pragma unroll
            for (int mr = 0; mr < 4; ++mr)
                af[mr] = *(const f16x8*)&As[wr + mr * 16 + lr][kk * 32 + kg * 8];
#pragma unroll
            for (int nc = 0; nc < 4; ++nc)
                bf[nc] = *(const f16x8*)&Bs[wc + nc * 16 + lr][kk * 32 + kg * 8];
#pragma unroll
            for (int mr = 0; mr < 4; ++mr)
#pragma unroll
                for (int nc = 0; nc < 4; ++nc)
                    acc[mr][nc] = __builtin_amdgcn_mfma_f32_16x16x32_f16(
                        af[mr], bf[nc], acc[mr][nc], 0, 0, 0);
        }
        __syncthreads();
    }
    // epilogue: D row = (lane>>4)*4 + j, col = lane&15
    const int r0 = m0 + wr + kg * 4;
    if (n0 < 256) {
#pragma unroll
        for (int mr = 0; mr < 4; ++mr)
#pragma unroll
            for (int nc = 0; nc < 4; ++nc) {
                int col = n0 + wc + nc * 16 + lr;
#pragma unroll
                for (int j = 0; j < 4; ++j)
                    scores[(r0 + mr * 16 + j) * 256 + col] = acc[mr][nc][j];
            }
    } else {
#pragma unroll
        for (int mr = 0; mr < 4; ++mr)
#pragma unroll
            for (int nc = 0; nc < 4; ++nc) {
                int col = n0 - 256 + wc + nc * 16 + lr;
#pragma unroll
                for (int j = 0; j < 4; ++j)
                    vh[(r0 + mr * 16 + j) * 256 + col] = (_Float16)acc[mr][nc][j];
            }
    }
}

// ---------------------------------------------------------------
// stats_partial: grid (B, 32) = 2048 blocks, ~16 edges each. ILP-4 in both
// passes. R6 fix: was (B,8), 1 dependent load/iter -> 47us latency-bound
// (471 GB/s, VALUBusy 5%).
__global__ __launch_bounds__(256) void stats_partial(const float* __restrict__ scores,
                                                     const int* __restrict__ batch,
                                                     float* __restrict__ mp,
                                                     float* __restrict__ sp) {
    const int b = blockIdx.x, c = blockIdx.y, t = threadIdx.x;
    const int e0 = lower_bound64(batch, b);
    const int e1 = lower_bound64(batch, b + 1);
    const int len = e1 - e0;
    const int cs = e0 + (len * c) / 32;
    const int ce = e0 + (len * (c + 1)) / 32;
    float m0 = -3.4e38f, m1 = -3.4e38f, m2 = -3.4e38f, m3 = -3.4e38f;
    int e = cs;
    for (; e + 4 <= ce; e += 4) {
        m0 = fmaxf(m0, scores[(e + 0) * 256 + t]);
        m1 = fmaxf(m1, scores[(e + 1) * 256 + t]);
        m2 = fmaxf(m2, scores[(e + 2) * 256 + t]);
        m3 = fmaxf(m3, scores[(e + 3) * 256 + t]);
    }
    for (; e < ce; ++e) m0 = fmaxf(m0, scores[e * 256 + t]);
    float m = fmaxf(fmaxf(m0, m1), fmaxf(m2, m3));
    float s0 = 0.f, s1 = 0.f, s2 = 0.f, s3 = 0.f;
    e = cs;
    for (; e + 4 <= ce; e += 4) {
        s0 += __expf(scores[(e + 0) * 256 + t] - m);
        s1 += __expf(scores[(e + 1) * 256 + t] - m);
        s2 += __expf(scores[(e + 2) * 256 + t] - m);
        s3 += __expf(scores[(e + 3) * 256 + t] - m);
    }
    for (; e < ce; ++e) s0 += __expf(scores[e * 256 + t] - m);
    mp[(b * 32 + c) * 256 + t] = m;
    sp[(b * 32 + c) * 256 + t] = (s0 + s1) + (s2 + s3);
}

// ---------------------------------------------------------------
__global__ __launch_bounds__(256) void stats_merge(const float* __restrict__ mp,
                                                   const float* __restrict__ sp,
                                                   float* __restrict__ mm,
                                                   float* __restrict__ di) {
    const int b = blockIdx.x, t = threadIdx.x;
    float m = -3.4e38f;
#pragma unroll
    for (int c = 0; c < 32; ++c) m = fmaxf(m, mp[(b * 32 + c) * 256 + t]);
    float d = 0.f;
#pragma unroll
    for (int c = 0; c < 32; ++c) {
        float sc = sp[(b * 32 + c) * 256 + t];
        if (sc > 0.f) d += sc * __expf(mp[(b * 32 + c) * 256 + t] - m);
    }
    mm[b * 256 + t] = m;
    di[b * 256 + t] = (d > 0.f) ? 1.f / d : 0.f;
}

// ---------------------------------------------------------------
// attend: grid (B, NH, 4). Per (graph, head, chunk): partial attended over
// ~len/4 edges, 32-edge LDS tiles; writes att4[c][b*32+s][nh*32+hd].
// dv applied per partial (constant per column -> sums correctly).
__global__ __launch_bounds__(256) void attend(const float* __restrict__ scores,
                                              const _Float16* __restrict__ vh,
                                              const int* __restrict__ batch,
                                              const float* __restrict__ mm,
                                              const float* __restrict__ di,
                                              float* __restrict__ att4) {
    const int b = blockIdx.x, nh = blockIdx.y, c = blockIdx.z, t = threadIdx.x;
    const int e0 = lower_bound64(batch, b);
    const int e1 = lower_bound64(batch, b + 1);
    const int len = e1 - e0;
    const int cs = e0 + (len * c) / 4;
    const int ce = e0 + (len * (c + 1)) / 4;
    __shared__ float wl[32][33];
    __shared__ float vl[32][33];
    __shared__ float mc[32], dc[32];
    if (t < 32) {
        mc[t] = mm[b * 256 + nh * 32 + t];
        dc[t] = di[b * 256 + nh * 32 + t];
    }
    __syncthreads();
    const int s = t & 31, g = t >> 5;      // compute mapping
    const int le = t >> 3, q = t & 7;      // stage mapping
    float acc0 = 0.f, acc1 = 0.f, acc2 = 0.f, acc3 = 0.f;
    for (int te = cs; te < ce; te += 32) {
        const int e = te + le;
        const bool ok = (e < ce);
        float4 x = make_float4(0.f, 0.f, 0.f, 0.f);
        f16x4 vv = {};
        if (ok) {
            x = *(const float4*)&scores[e * 256 + nh * 32 + q * 4];
            vv = *(const f16x4*)&vh[e * 256 + nh * 32 + q * 4];
        }
        wl[le][q * 4 + 0] = ok ? __expf(x.x - mc[q * 4 + 0]) : 0.f;
        wl[le][q * 4 + 1] = ok ? __expf(x.y - mc[q * 4 + 1]) : 0.f;
        wl[le][q * 4 + 2] = ok ? __expf(x.z - mc[q * 4 + 2]) : 0.f;
        wl[le][q * 4 + 3] = ok ? __expf(x.w - mc[q * 4 + 3]) : 0.f;
        vl[le][q * 4 + 0] = ok ? (float)vv[0] : 0.f;
        vl[le][q * 4 + 1] = ok ? (float)vv[1] : 0.f;
        vl[le][q * 4 + 2] = ok ? (float)vv[2] : 0.f;
        vl[le][q * 4 + 3] = ok ? (float)vv[3] : 0.f;
        __syncthreads();
#pragma unroll
        for (int e2 = 0; e2 < 32; ++e2) {
            float wv = wl[e2][s];
            acc0 += wv * vl[e2][g * 4 + 0];
            acc1 += wv * vl[e2][g * 4 + 1];
            acc2 += wv * vl[e2][g * 4 + 2];
            acc3 += wv * vl[e2][g * 4 + 3];
        }
        __syncthreads();
    }
    const float dv = dc[s];
    float* op = &att4[((size_t)c * 2048 + b * 32 + s) * 256 + nh * 32 + g * 4];
    op[0] = acc0 * dv; op[1] = acc1 * dv; op[2] = acc2 * dv; op[3] = acc3 * dv;
}

// ---------------------------------------------------------------
// attend_reduce: att[i] = sum_c att4[c][i]; 524288 floats, float4 per thread.
__global__ __launch_bounds__(256) void attend_reduce(const float* __restrict__ att4,
                                                     float* __restrict__ att) {
    const int i = (blockIdx.x * 256 + threadIdx.x) * 4;
    float4 a = *(const float4*)&att4[i];
    float4 b = *(const float4*)&att4[524288 + i];
    float4 c = *(const float4*)&att4[2 * 524288 + i];
    float4 d = *(const float4*)&att4[3 * 524288 + i];
    *(float4*)&att[i] = make_float4(a.x + b.x + c.x + d.x, a.y + b.y + c.y + d.y,
                                    a.z + b.z + c.z + d.z, a.w + b.w + c.w + d.w);
}

// ---------------------------------------------------------------
// fp32 GEMM C[r][c] = sum_k A[r][k]*W[c][k] (+bias), K=256. (Wo / W2 — small)
__global__ __launch_bounds__(256) void gemm_abT(const float* __restrict__ A,
                                                const float* __restrict__ W,
                                                const float* __restrict__ bias,
                                                float* __restrict__ out0) {
    __shared__ float As[16][64];
    __shared__ float Bs[16][64];
    const int tid = threadIdx.x;
    const int m0 = blockIdx.y * 64, n0 = blockIdx.x * 64;
    const int tx = tid & 15, ty = tid >> 4;
    const int lrow = tid >> 2;
    const int lkq = (tid & 3) * 4;
    float acc[4][4];
#pragma unroll
    for (int i = 0; i < 4; ++i)
#pragma unroll
        for (int j = 0; j < 4; ++j) acc[i][j] = 0.f;

    for (int k0 = 0; k0 < 256; k0 += 16) {
        float4 av = *(const float4*)&A[(m0 + lrow) * 256 + k0 + lkq];
        float4 wv = *(const float4*)&W[(n0 + lrow) * 256 + k0 + lkq];
        As[lkq + 0][lrow] = av.x; As[lkq + 1][lrow] = av.y;
        As[lkq + 2][lrow] = av.z; As[lkq + 3][lrow] = av.w;
        Bs[lkq + 0][lrow] = wv.x; Bs[lkq + 1][lrow] = wv.y;
        Bs[lkq + 2][lrow] = wv.z; Bs[lkq + 3][lrow] = wv.w;
        __syncthreads();
#pragma unroll
        for (int k = 0; k < 16; ++k) {
            float4 a4 = *(const float4*)&As[k][ty * 4];
            float4 b4 = *(const float4*)&Bs[k][tx * 4];
            acc[0][0] += a4.x * b4.x; acc[0][1] += a4.x * b4.y;
            acc[0][2] += a4.x * b4.z; acc[0][3] += a4.x * b4.w;
            acc[1][0] += a4.y * b4.x; acc[1][1] += a4.y * b4.y;
            acc[1][2] += a4.y * b4.z; acc[1][3] += a4.y * b4.w;
            acc[2][0] += a4.z * b4.x; acc[2][1] += a4.z * b4.y;
            acc[2][2] += a4.z * b4.z; acc[2][3] += a4.z * b4.w;
            acc[3][0] += a4.w * b4.x; acc[3][1] += a4.w * b4.y;
            acc[3][2] += a4.w * b4.z; acc[3][3] += a4.w * b4.w;
        }
        __syncthreads();
    }
    const int c = n0 + tx * 4;
    float4 bb = bias ? *(const float4*)&bias[c]
                     : make_float4(0.f, 0.f, 0.f, 0.f);
#pragma unroll
    for (int mi = 0; mi < 4; ++mi) {
        int r = m0 + ty * 4 + mi;
        float4 o = make_float4(acc[mi][0] + bb.x, acc[mi][1] + bb.y,
                               acc[mi][2] + bb.z, acc[mi][3] + bb.w);
        *(float4*)&out0[r * 256 + c] = o;
    }
}

// ---------------------------------------------------------------
// W1 split-K: 64 k-splits of 128. grid (4, 64) = 256 blocks.
__global__ __launch_bounds__(256) void gemm_w1_splitk(const float* __restrict__ flat,
                                                      const float* __restrict__ W1,
                                                      float* __restrict__ partials) {
    __shared__ float As[16][64];
    __shared__ float Bs[16][64];
    const int tid = threadIdx.x;
    const int n0 = blockIdx.x * 64;
    const int kbase = blockIdx.y * 128;
    const int tx = tid & 15, ty = tid >> 4;
    const int lrow = tid >> 2, lkq = (tid & 3) * 4;
    float acc[4][4];
#pragma unroll
    for (int i = 0; i < 4; ++i)
#pragma unroll
        for (int j = 0; j < 4; ++j) acc[i][j] = 0.f;

    for (int k0 = 0; k0 < 128; k0 += 16) {
        float4 av = *(const float4*)&flat[lrow * 8192 + kbase + k0 + lkq];
        float4 wv = *(const float4*)&W1[(n0 + lrow) * 8192 + kbase + k0 + lkq];
        As[lkq + 0][lrow] = av.x; As[lkq + 1][lrow] = av.y;
        As[lkq + 2][lrow] = av.z; As[lkq + 3][lrow] = av.w;
        Bs[lkq + 0][lrow] = wv.x; Bs[lkq + 1][lrow] = wv.y;
        Bs[lkq + 2][lrow] = wv.z; Bs[lkq + 3][lrow] = wv.w;
        __syncthreads();
#pragma unroll
        for (int k = 0; k < 16; ++k) {
            float4 a4 = *(const float4*)&As[k][ty * 4];
            float4 b4 = *(const float4*)&Bs[k][tx * 4];
            acc[0][0] += a4.x * b4.x; acc[0][1] += a4.x * b4.y;
            acc[0][2] += a4.x * b4.z; acc[0][3] += a4.x * b4.w;
            acc[1][0] += a4.y * b4.x; acc[1][1] += a4.y * b4.y;
            acc[1][2] += a4.y * b4.z; acc[1][3] += a4.y * b4.w;
            acc[2][0] += a4.z * b4.x; acc[2][1] += a4.z * b4.y;
            acc[2][2] += a4.z * b4.z; acc[2][3] += a4.z * b4.w;
            acc[3][0] += a4.w * b4.x; acc[3][1] += a4.w * b4.y;
            acc[3][2] += a4.w * b4.z; acc[3][3] += a4.w * b4.w;
        }
        __syncthreads();
    }
#pragma unroll
    for (int mi = 0; mi < 4; ++mi) {
        int bb = ty * 4 + mi;
        *(float4*)&partials[blockIdx.y * 16384 + bb * 256 + n0 + tx * 4] =
            make_float4(acc[mi][0], acc[mi][1], acc[mi][2], acc[mi][3]);
    }
}

// ---------------------------------------------------------------
__global__ void silu_reduce(const float* __restrict__ partials,
                            const float* __restrict__ b1,
                            float* __restrict__ h1) {
    int t = blockIdx.x * 256 + threadIdx.x;  // 0..16383
    float s0 = b1[t & 255], s1 = 0.f, s2 = 0.f, s3 = 0.f;
#pragma unroll
    for (int ks = 0; ks < 64; ks += 4) {
        s0 += partials[(ks + 0) * 16384 + t];
        s1 += partials[(ks + 1) * 16384 + t];
        s2 += partials[(ks + 2) * 16384 + t];
        s3 += partials[(ks + 3) * 16384 + t];
    }
    float sum = (s0 + s1) + (s2 + s3);
    h1[t] = sum / (1.f + __expf(-sum));
}

// ---------------------------------------------------------------
extern "C" void kernel_launch(void* const* d_in, const int* in_sizes, int n_in,
                              void* d_out, int out_size, void* d_ws, size_t ws_size,
                              hipStream_t stream) {
    const float* X     = (const float*)d_in[0];
    const int*   batch = (const int*)d_in[2];
    const float* seed  = (const float*)d_in[3];
    const float* Wq    = (const float*)d_in[4];
    const float* Wk    = (const float*)d_in[5];
    const float* Wv    = (const float*)d_in[6];
    const float* Wo    = (const float*)d_in[7];
    const float* bo    = (const float*)d_in[8];
    const float* W1    = (const float*)d_in[9];
    const float* b1    = (const float*)d_in[10];
    const float* W2    = (const float*)d_in[11];
    const float* b2    = (const float*)d_in[12];
    float* out = (float*)d_out;
    float* ws = (float*)d_ws;

    _Float16* Mth   = (_Float16*)(ws + OFF_MTH);
    float* mm       = ws + OFF_MM;
    float* di       = ws + OFF_DI;
    float* mp       = ws + OFF_MP;
    float* sp       = ws + OFF_SP;
    float* att4     = ws + OFF_ATT4;
    float* att      = ws + OFF_ATT;
    float* gr       = ws + OFF_GR;
    float* part     = ws + OFF_PART;
    float* h1       = ws + OFF_H1;
    float* scores   = ws + OFF_SCORES;
    _Float16* vh    = (_Float16*)(ws + OFF_VH);

    hipLaunchKernelGGL(prep, dim3(16), dim3(256), 0, stream, seed, Wq, Wk, Wv, Mth);
    // scores (f32) + v (f16): [E,256]@[256,512] via f16 MFMA
    hipLaunchKernelGGL(gemm16, dim3(4, 256), dim3(256), 0, stream, X, Mth, scores, vh);
    hipLaunchKernelGGL(stats_partial, dim3(64, 32), dim3(256), 0, stream, scores, batch, mp, sp);
    hipLaunchKernelGGL(stats_merge, dim3(64), dim3(256), 0, stream, mp, sp, mm, di);
    hipLaunchKernelGGL(attend, dim3(64, 8, 4), dim3(256), 0, stream, scores, vh, batch, mm, di, att4);
    hipLaunchKernelGGL(attend_reduce, dim3(512), dim3(256), 0, stream, att4, att);
    // graph_repr = att @ Wo^T + bo   [2048,256]
    hipLaunchKernelGGL(gemm_abT, dim3(4, 32), dim3(256), 0, stream, att, Wo, bo, gr);
    // h1_pre split-K over K=8192, 64-way split (256 blocks)
    hipLaunchKernelGGL(gemm_w1_splitk, dim3(4, 64), dim3(256), 0, stream, gr, W1, part);
    hipLaunchKernelGGL(silu_reduce, dim3(64), dim3(256), 0, stream, part, b1, h1);
    // out = h1 @ W2^T + b2   [64,256]
    hipLaunchKernelGGL(gemm_abT, dim3(4, 1), dim3(256), 0, stream, h1, W2, b2, out);
}

// Round 15
// 234.939 us; speedup vs baseline: 3.2161x; 1.0535x over previous
//
#include <hip/hip_runtime.h>
#include <hip/hip_bf16.h>

#define E_N 32768
#define H_N 256
#define S_N 32
#define NH_N 8
#define B_N 64

typedef _Float16 f16x8 __attribute__((ext_vector_type(8)));
typedef _Float16 f16x4 __attribute__((ext_vector_type(4)));
typedef float    f32x4 __attribute__((ext_vector_type(4)));

// ---- workspace layout (float offsets) ----
#define OFF_MTH    0                  // 512*256 f16 = 65536 floats
#define OFF_MM     65536              // 64*256
#define OFF_DI     81920              // 64*256
#define OFF_MP     98304              // 64*32*256 = 524288
#define OFF_SP     622592             // 64*32*256 = 524288
#define OFF_ATT4   98304              // 4*2048*256 = 2097152 (overlays MP/SP after merge)
#define OFF_GR     2195456            // 524288
#define OFF_PART   2719744            // 64*16384 = 1048576
#define OFF_H1     3768320            // 16384
#define OFF_SCORES 3784704            // E*256 f32 = 8388608
#define OFF_VH     12173312           // E*256 f16 = 2097152 floats
#define OFF_XH     14270464           // E*256 f16 = 4194304 floats
// total 18464768 floats = 73.9 MB (ws alloc >= 256MiB per harness fill evidence)

__device__ inline int lower_bound64(const int* __restrict__ batch, int b) {
    int lo = 0, hi = E_N;
    while (lo < hi) { int mid = (lo + hi) >> 1; if (batch[mid] < b) lo = mid + 1; else hi = mid; }
    return lo;
}

// ---------------------------------------------------------------
// xcvt: X f32 -> f16 once (R7: removes per-K-step cvt VALU from gemm16 and
// halves its A-panel HBM re-reads).
__global__ __launch_bounds__(256) void xcvt(const float* __restrict__ X,
                                            _Float16* __restrict__ Xh) {
    const int i = (blockIdx.x * 256 + threadIdx.x) * 8;
    float4 a = *(const float4*)&X[i];
    float4 b = *(const float4*)&X[i + 4];
    f16x8 h;
    h[0] = (_Float16)a.x; h[1] = (_Float16)a.y; h[2] = (_Float16)a.z; h[3] = (_Float16)a.w;
    h[4] = (_Float16)b.x; h[5] = (_Float16)b.y; h[6] = (_Float16)b.z; h[7] = (_Float16)b.w;
    *(f16x8*)&Xh[i] = h;
}

// ---------------------------------------------------------------
// prep: blocks 0..7 compute q-head + Mth QK rows; blocks 8..15 copy Wv->f16.
// R7: seed staged in LDS + float4 j-loop (was scalar 256-iter latency chain).
__global__ __launch_bounds__(256) void prep(const float* __restrict__ seed,
                                            const float* __restrict__ Wq,
                                            const float* __restrict__ Wk,
                                            const float* __restrict__ Wv,
                                            _Float16* __restrict__ Mth) {
    const int t = threadIdx.x, bid = blockIdx.x;
    __shared__ float sld[32][256];   // 32KB seed copy
    __shared__ float q_l[32][32];    // [s][d]
    if (bid < 8) {
        const int nh = bid;
        for (int i = t; i < 2048; i += 256) {       // 2048 float4 = full seed
            int r = i >> 6, c4 = (i & 63) * 4;
            *(float4*)&sld[r][c4] = *(const float4*)&seed[r * 256 + c4];
        }
        __syncthreads();
        const int d = t & 31, s0 = t >> 5;
        const float4* wq4 = (const float4*)&Wq[(nh * 32 + d) * 256];
        float a0 = 0, a1 = 0, a2 = 0, a3 = 0;
#pragma unroll 8
        for (int j4 = 0; j4 < 64; ++j4) {
            float4 w = wq4[j4];
            const int j = j4 * 4;
            a0 += w.x * sld[s0][j] + w.y * sld[s0][j + 1] + w.z * sld[s0][j + 2] + w.w * sld[s0][j + 3];
            a1 += w.x * sld[s0 + 8][j] + w.y * sld[s0 + 8][j + 1] + w.z * sld[s0 + 8][j + 2] + w.w * sld[s0 + 8][j + 3];
            a2 += w.x * sld[s0 + 16][j] + w.y * sld[s0 + 16][j + 1] + w.z * sld[s0 + 16][j + 2] + w.w * sld[s0 + 16][j + 3];
            a3 += w.x * sld[s0 + 24][j] + w.y * sld[s0 + 24][j + 1] + w.z * sld[s0 + 24][j + 2] + w.w * sld[s0 + 24][j + 3];
        }
        q_l[s0][d] = a0; q_l[s0 + 8][d] = a1; q_l[s0 + 16][d] = a2; q_l[s0 + 24][d] = a3;
        __syncthreads();
        float acc[32];
#pragma unroll
        for (int s = 0; s < 32; ++s) acc[s] = 0.f;
        for (int dd = 0; dd < 32; ++dd) {
            float w = Wk[(nh * 32 + dd) * 256 + t];
#pragma unroll
            for (int s = 0; s < 32; ++s) acc[s] += w * q_l[s][dd];
        }
        const float scale = 0.17677669529663687f;  // 1/sqrt(32)
        for (int s = 0; s < 32; ++s)
            Mth[(nh * 32 + s) * 256 + t] = (_Float16)(acc[s] * scale);
    } else {
        const int j0 = (bid - 8) * 32;
        for (int jj = 0; jj < 32; ++jj)
            Mth[(256 + j0 + jj) * 256 + t] = (_Float16)Wv[(j0 + jj) * 256 + t];
    }
}

// ---------------------------------------------------------------
// f16 MFMA GEMM: C[r][c] = sum_k Xh[r][k]*Mth[c][k];  r<E, c<512.
// cols 0..255 -> scores (f32); cols 256..511 -> vh (f16).
// R7: A staged as raw uint4 from pre-converted Xh (no in-loop cvt).
__global__ __launch_bounds__(256) void gemm16(const _Float16* __restrict__ Xh,
                                              const _Float16* __restrict__ Mth,
                                              float* __restrict__ scores,
                                              _Float16* __restrict__ vh) {
    __shared__ _Float16 As[128][72];   // 144B row stride
    __shared__ _Float16 Bs[128][72];
    const int tid = threadIdx.x;
    const int n0 = blockIdx.x * 128;
    const int m0 = blockIdx.y * 128;
    const int w = tid >> 6, l = tid & 63;
    const int lr = l & 15, kg = l >> 4;
    const int wr = (w & 1) * 64, wc = (w >> 1) * 64;
    f32x4 acc[4][4] = {};

    for (int ks = 0; ks < 4; ++ks) {
        const int k0 = ks * 64;
#pragma unroll
        for (int i = 0; i < 4; ++i) {
            int idx = tid + i * 256;          // 0..1023
            int row = idx >> 3, c8 = (idx & 7) * 8;
            *(uint4*)&As[row][c8] = *(const uint4*)&Xh[(m0 + row) * 256 + k0 + c8];
        }
#pragma unroll
        for (int i = 0; i < 4; ++i) {
            int idx = tid + i * 256;          // 0..1023
            int row = idx >> 3, c8 = (idx & 7) * 8;
            *(uint4*)&Bs[row][c8] = *(const uint4*)&Mth[(n0 + row) * 256 + k0 + c8];
        }
        __syncthreads();
#pragma unroll
        for (int kk = 0; kk < 2; ++kk) {
            f16x8 af[4], bf[4];
#pragma unroll
            for (int mr = 0; mr < 4; ++mr)
                af[mr] = *(const f16x8*)&As[wr + mr * 16 + lr][kk * 32 + kg * 8];
#pragma unroll
            for (int nc = 0; nc < 4; ++nc)
                bf[nc] = *(const f16x8*)&Bs[wc + nc * 16 + lr][kk * 32 + kg * 8];
#pragma unroll
            for (int mr = 0; mr < 4; ++mr)
#pragma unroll
                for (int nc = 0; nc < 4; ++nc)
                    acc[mr][nc] = __builtin_amdgcn_mfma_f32_16x16x32_f16(
                        af[mr], bf[nc], acc[mr][nc], 0, 0, 0);
        }
        __syncthreads();
    }
    // epilogue: D row = (lane>>4)*4 + j, col = lane&15
    const int r0 = m0 + wr + kg * 4;
    if (n0 < 256) {
#pragma unroll
        for (int mr = 0; mr < 4; ++mr)
#pragma unroll
            for (int nc = 0; nc < 4; ++nc) {
                int col = n0 + wc + nc * 16 + lr;
#pragma unroll
                for (int j = 0; j < 4; ++j)
                    scores[(r0 + mr * 16 + j) * 256 + col] = acc[mr][nc][j];
            }
    } else {
#pragma unroll
        for (int mr = 0; mr < 4; ++mr)
#pragma unroll
            for (int nc = 0; nc < 4; ++nc) {
                int col = n0 - 256 + wc + nc * 16 + lr;
#pragma unroll
                for (int j = 0; j < 4; ++j)
                    vh[(r0 + mr * 16 + j) * 256 + col] = (_Float16)acc[mr][nc][j];
            }
    }
}

// ---------------------------------------------------------------
// stats_partial: grid (B, 32) = 2048 blocks, ~16 edges each, ILP-4.
__global__ __launch_bounds__(256) void stats_partial(const float* __restrict__ scores,
                                                     const int* __restrict__ batch,
                                                     float* __restrict__ mp,
                                                     float* __restrict__ sp) {
    const int b = blockIdx.x, c = blockIdx.y, t = threadIdx.x;
    const int e0 = lower_bound64(batch, b);
    const int e1 = lower_bound64(batch, b + 1);
    const int len = e1 - e0;
    const int cs = e0 + (len * c) / 32;
    const int ce = e0 + (len * (c + 1)) / 32;
    float m0 = -3.4e38f, m1 = -3.4e38f, m2 = -3.4e38f, m3 = -3.4e38f;
    int e = cs;
    for (; e + 4 <= ce; e += 4) {
        m0 = fmaxf(m0, scores[(e + 0) * 256 + t]);
        m1 = fmaxf(m1, scores[(e + 1) * 256 + t]);
        m2 = fmaxf(m2, scores[(e + 2) * 256 + t]);
        m3 = fmaxf(m3, scores[(e + 3) * 256 + t]);
    }
    for (; e < ce; ++e) m0 = fmaxf(m0, scores[e * 256 + t]);
    float m = fmaxf(fmaxf(m0, m1), fmaxf(m2, m3));
    float s0 = 0.f, s1 = 0.f, s2 = 0.f, s3 = 0.f;
    e = cs;
    for (; e + 4 <= ce; e += 4) {
        s0 += __expf(scores[(e + 0) * 256 + t] - m);
        s1 += __expf(scores[(e + 1) * 256 + t] - m);
        s2 += __expf(scores[(e + 2) * 256 + t] - m);
        s3 += __expf(scores[(e + 3) * 256 + t] - m);
    }
    for (; e < ce; ++e) s0 += __expf(scores[e * 256 + t] - m);
    mp[(b * 32 + c) * 256 + t] = m;
    sp[(b * 32 + c) * 256 + t] = (s0 + s1) + (s2 + s3);
}

// ---------------------------------------------------------------
__global__ __launch_bounds__(256) void stats_merge(const float* __restrict__ mp,
                                                   const float* __restrict__ sp,
                                                   float* __restrict__ mm,
                                                   float* __restrict__ di) {
    const int b = blockIdx.x, t = threadIdx.x;
    float m = -3.4e38f;
#pragma unroll
    for (int c = 0; c < 32; ++c) m = fmaxf(m, mp[(b * 32 + c) * 256 + t]);
    float d = 0.f;
#pragma unroll
    for (int c = 0; c < 32; ++c) {
        float sc = sp[(b * 32 + c) * 256 + t];
        if (sc > 0.f) d += sc * __expf(mp[(b * 32 + c) * 256 + t] - m);
    }
    mm[b * 256 + t] = m;
    di[b * 256 + t] = (d > 0.f) ? 1.f / d : 0.f;
}

// ---------------------------------------------------------------
// attend: grid (B, NH, 4); partial attended into att4[c] (reduced in Wo GEMM).
__global__ __launch_bounds__(256) void attend(const float* __restrict__ scores,
                                              const _Float16* __restrict__ vh,
                                              const int* __restrict__ batch,
                                              const float* __restrict__ mm,
                                              const float* __restrict__ di,
                                              float* __restrict__ att4) {
    const int b = blockIdx.x, nh = blockIdx.y, c = blockIdx.z, t = threadIdx.x;
    const int e0 = lower_bound64(batch, b);
    const int e1 = lower_bound64(batch, b + 1);
    const int len = e1 - e0;
    const int cs = e0 + (len * c) / 4;
    const int ce = e0 + (len * (c + 1)) / 4;
    __shared__ float wl[32][33];
    __shared__ float vl[32][33];
    __shared__ float mc[32], dc[32];
    if (t < 32) {
        mc[t] = mm[b * 256 + nh * 32 + t];
        dc[t] = di[b * 256 + nh * 32 + t];
    }
    __syncthreads();
    const int s = t & 31, g = t >> 5;
    const int le = t >> 3, q = t & 7;
    float acc0 = 0.f, acc1 = 0.f, acc2 = 0.f, acc3 = 0.f;
    for (int te = cs; te < ce; te += 32) {
        const int e = te + le;
        const bool ok = (e < ce);
        float4 x = make_float4(0.f, 0.f, 0.f, 0.f);
        f16x4 vv = {};
        if (ok) {
            x = *(const float4*)&scores[e * 256 + nh * 32 + q * 4];
            vv = *(const f16x4*)&vh[e * 256 + nh * 32 + q * 4];
        }
        wl[le][q * 4 + 0] = ok ? __expf(x.x - mc[q * 4 + 0]) : 0.f;
        wl[le][q * 4 + 1] = ok ? __expf(x.y - mc[q * 4 + 1]) : 0.f;
        wl[le][q * 4 + 2] = ok ? __expf(x.z - mc[q * 4 + 2]) : 0.f;
        wl[le][q * 4 + 3] = ok ? __expf(x.w - mc[q * 4 + 3]) : 0.f;
        vl[le][q * 4 + 0] = ok ? (float)vv[0] : 0.f;
        vl[le][q * 4 + 1] = ok ? (float)vv[1] : 0.f;
        vl[le][q * 4 + 2] = ok ? (float)vv[2] : 0.f;
        vl[le][q * 4 + 3] = ok ? (float)vv[3] : 0.f;
        __syncthreads();
#pragma unroll
        for (int e2 = 0; e2 < 32; ++e2) {
            float wv = wl[e2][s];
            acc0 += wv * vl[e2][g * 4 + 0];
            acc1 += wv * vl[e2][g * 4 + 1];
            acc2 += wv * vl[e2][g * 4 + 2];
            acc3 += wv * vl[e2][g * 4 + 3];
        }
        __syncthreads();
    }
    const float dv = dc[s];
    float* op = &att4[((size_t)c * 524288) + (b * 32 + s) * 256 + nh * 32 + g * 4];
    op[0] = acc0 * dv; op[1] = acc1 * dv; op[2] = acc2 * dv; op[3] = acc3 * dv;
}

// ---------------------------------------------------------------
// Wo GEMM with fused att4 4-way reduce in the A-stage (R7: kills
// attend_reduce launch + 4MB round trip). gr = (sum_c att4[c]) @ Wo^T + bo.
__global__ __launch_bounds__(256) void gemm_wo(const float* __restrict__ att4,
                                               const float* __restrict__ W,
                                               const float* __restrict__ bias,
                                               float* __restrict__ out0) {
    __shared__ float As[16][64];
    __shared__ float Bs[16][64];
    const int tid = threadIdx.x;
    const int m0 = blockIdx.y * 64, n0 = blockIdx.x * 64;
    const int tx = tid & 15, ty = tid >> 4;
    const int lrow = tid >> 2;
    const int lkq = (tid & 3) * 4;
    float acc[4][4];
#pragma unroll
    for (int i = 0; i < 4; ++i)
#pragma unroll
        for (int j = 0; j < 4; ++j) acc[i][j] = 0.f;

    for (int k0 = 0; k0 < 256; k0 += 16) {
        const int ai = (m0 + lrow) * 256 + k0 + lkq;
        float4 a0 = *(const float4*)&att4[ai];
        float4 a1 = *(const float4*)&att4[524288 + ai];
        float4 a2 = *(const float4*)&att4[2 * 524288 + ai];
        float4 a3 = *(const float4*)&att4[3 * 524288 + ai];
        float4 av = make_float4(a0.x + a1.x + a2.x + a3.x, a0.y + a1.y + a2.y + a3.y,
                                a0.z + a1.z + a2.z + a3.z, a0.w + a1.w + a2.w + a3.w);
        float4 wv = *(const float4*)&W[(n0 + lrow) * 256 + k0 + lkq];
        As[lkq + 0][lrow] = av.x; As[lkq + 1][lrow] = av.y;
        As[lkq + 2][lrow] = av.z; As[lkq + 3][lrow] = av.w;
        Bs[lkq + 0][lrow] = wv.x; Bs[lkq + 1][lrow] = wv.y;
        Bs[lkq + 2][lrow] = wv.z; Bs[lkq + 3][lrow] = wv.w;
        __syncthreads();
#pragma unroll
        for (int k = 0; k < 16; ++k) {
            float4 a4 = *(const float4*)&As[k][ty * 4];
            float4 b4 = *(const float4*)&Bs[k][tx * 4];
            acc[0][0] += a4.x * b4.x; acc[0][1] += a4.x * b4.y;
            acc[0][2] += a4.x * b4.z; acc[0][3] += a4.x * b4.w;
            acc[1][0] += a4.y * b4.x; acc[1][1] += a4.y * b4.y;
            acc[1][2] += a4.y * b4.z; acc[1][3] += a4.y * b4.w;
            acc[2][0] += a4.z * b4.x; acc[2][1] += a4.z * b4.y;
            acc[2][2] += a4.z * b4.z; acc[2][3] += a4.z * b4.w;
            acc[3][0] += a4.w * b4.x; acc[3][1] += a4.w * b4.y;
            acc[3][2] += a4.w * b4.z; acc[3][3] += a4.w * b4.w;
        }
        __syncthreads();
    }
    const int c = n0 + tx * 4;
    float4 bb = *(const float4*)&bias[c];
#pragma unroll
    for (int mi = 0; mi < 4; ++mi) {
        int r = m0 + ty * 4 + mi;
        float4 o = make_float4(acc[mi][0] + bb.x, acc[mi][1] + bb.y,
                               acc[mi][2] + bb.z, acc[mi][3] + bb.w);
        *(float4*)&out0[r * 256 + c] = o;
    }
}

// ---------------------------------------------------------------
// W1 split-K: 64 k-splits of 128. grid (4, 64) = 256 blocks.
__global__ __launch_bounds__(256) void gemm_w1_splitk(const float* __restrict__ flat,
                                                      const float* __restrict__ W1,
                                                      float* __restrict__ partials) {
    __shared__ float As[16][64];
    __shared__ float Bs[16][64];
    const int tid = threadIdx.x;
    const int n0 = blockIdx.x * 64;
    const int kbase = blockIdx.y * 128;
    const int tx = tid & 15, ty = tid >> 4;
    const int lrow = tid >> 2, lkq = (tid & 3) * 4;
    float acc[4][4];
#pragma unroll
    for (int i = 0; i < 4; ++i)
#pragma unroll
        for (int j = 0; j < 4; ++j) acc[i][j] = 0.f;

    for (int k0 = 0; k0 < 128; k0 += 16) {
        float4 av = *(const float4*)&flat[lrow * 8192 + kbase + k0 + lkq];
        float4 wv = *(const float4*)&W1[(n0 + lrow) * 8192 + kbase + k0 + lkq];
        As[lkq + 0][lrow] = av.x; As[lkq + 1][lrow] = av.y;
        As[lkq + 2][lrow] = av.z; As[lkq + 3][lrow] = av.w;
        Bs[lkq + 0][lrow] = wv.x; Bs[lkq + 1][lrow] = wv.y;
        Bs[lkq + 2][lrow] = wv.z; Bs[lkq + 3][lrow] = wv.w;
        __syncthreads();
#pragma unroll
        for (int k = 0; k < 16; ++k) {
            float4 a4 = *(const float4*)&As[k][ty * 4];
            float4 b4 = *(const float4*)&Bs[k][tx * 4];
            acc[0][0] += a4.x * b4.x; acc[0][1] += a4.x * b4.y;
            acc[0][2] += a4.x * b4.z; acc[0][3] += a4.x * b4.w;
            acc[1][0] += a4.y * b4.x; acc[1][1] += a4.y * b4.y;
            acc[1][2] += a4.y * b4.z; acc[1][3] += a4.y * b4.w;
            acc[2][0] += a4.z * b4.x; acc[2][1] += a4.z * b4.y;
            acc[2][2] += a4.z * b4.z; acc[2][3] += a4.z * b4.w;
            acc[3][0] += a4.w * b4.x; acc[3][1] += a4.w * b4.y;
            acc[3][2] += a4.w * b4.z; acc[3][3] += a4.w * b4.w;
        }
        __syncthreads();
    }
#pragma unroll
    for (int mi = 0; mi < 4; ++mi) {
        int bb = ty * 4 + mi;
        *(float4*)&partials[blockIdx.y * 16384 + bb * 256 + n0 + tx * 4] =
            make_float4(acc[mi][0], acc[mi][1], acc[mi][2], acc[mi][3]);
    }
}

// ---------------------------------------------------------------
__global__ void silu_reduce(const float* __restrict__ partials,
                            const float* __restrict__ b1,
                            float* __restrict__ h1) {
    int t = blockIdx.x * 256 + threadIdx.x;  // 0..16383
    float s0 = b1[t & 255], s1 = 0.f, s2 = 0.f, s3 = 0.f;
#pragma unroll
    for (int ks = 0; ks < 64; ks += 4) {
        s0 += partials[(ks + 0) * 16384 + t];
        s1 += partials[(ks + 1) * 16384 + t];
        s2 += partials[(ks + 2) * 16384 + t];
        s3 += partials[(ks + 3) * 16384 + t];
    }
    float sum = (s0 + s1) + (s2 + s3);
    h1[t] = sum / (1.f + __expf(-sum));
}

// ---------------------------------------------------------------
// W2 GEMM [64,256]@[256,256]^T: 64 blocks, barrier-free, one output/thread.
// R7: was gemm_abT grid (4,1) = 4 blocks, latency-bound.
__global__ __launch_bounds__(256) void gemm_w2(const float* __restrict__ h1,
                                               const float* __restrict__ W2,
                                               const float* __restrict__ b2,
                                               float* __restrict__ out) {
    const int t = threadIdx.x;
    const int b = t & 63, cc = blockIdx.x * 4 + (t >> 6);
    const float4* hv = (const float4*)&h1[b * 256];
    const float4* wv = (const float4*)&W2[cc * 256];
    float a0 = 0, a1 = 0, a2 = 0, a3 = 0;
#pragma unroll 8
    for (int k = 0; k < 64; k += 4) {
        float4 h0 = hv[k + 0], w0 = wv[k + 0];
        a0 += h0.x * w0.x + h0.y * w0.y + h0.z * w0.z + h0.w * w0.w;
        float4 h1_ = hv[k + 1], w1 = wv[k + 1];
        a1 += h1_.x * w1.x + h1_.y * w1.y + h1_.z * w1.z + h1_.w * w1.w;
        float4 h2 = hv[k + 2], w2 = wv[k + 2];
        a2 += h2.x * w2.x + h2.y * w2.y + h2.z * w2.z + h2.w * w2.w;
        float4 h3 = hv[k + 3], w3 = wv[k + 3];
        a3 += h3.x * w3.x + h3.y * w3.y + h3.z * w3.z + h3.w * w3.w;
    }
    out[b * 256 + cc] = (a0 + a1) + (a2 + a3) + b2[cc];
}

// ---------------------------------------------------------------
extern "C" void kernel_launch(void* const* d_in, const int* in_sizes, int n_in,
                              void* d_out, int out_size, void* d_ws, size_t ws_size,
                              hipStream_t stream) {
    const float* X     = (const float*)d_in[0];
    const int*   batch = (const int*)d_in[2];
    const float* seed  = (const float*)d_in[3];
    const float* Wq    = (const float*)d_in[4];
    const float* Wk    = (const float*)d_in[5];
    const float* Wv    = (const float*)d_in[6];
    const float* Wo    = (const float*)d_in[7];
    const float* bo    = (const float*)d_in[8];
    const float* W1    = (const float*)d_in[9];
    const float* b1    = (const float*)d_in[10];
    const float* W2    = (const float*)d_in[11];
    const float* b2    = (const float*)d_in[12];
    float* out = (float*)d_out;
    float* ws = (float*)d_ws;

    _Float16* Mth   = (_Float16*)(ws + OFF_MTH);
    float* mm       = ws + OFF_MM;
    float* di       = ws + OFF_DI;
    float* mp       = ws + OFF_MP;
    float* sp       = ws + OFF_SP;
    float* att4     = ws + OFF_ATT4;
    float* gr       = ws + OFF_GR;
    float* part     = ws + OFF_PART;
    float* h1       = ws + OFF_H1;
    float* scores   = ws + OFF_SCORES;
    _Float16* vh    = (_Float16*)(ws + OFF_VH);
    _Float16* Xh    = (_Float16*)(ws + OFF_XH);

    hipLaunchKernelGGL(prep, dim3(16), dim3(256), 0, stream, seed, Wq, Wk, Wv, Mth);
    hipLaunchKernelGGL(xcvt, dim3(4096), dim3(256), 0, stream, X, Xh);
    // scores (f32) + v (f16): [E,256]@[256,512] via f16 MFMA
    hipLaunchKernelGGL(gemm16, dim3(4, 256), dim3(256), 0, stream, Xh, Mth, scores, vh);
    hipLaunchKernelGGL(stats_partial, dim3(64, 32), dim3(256), 0, stream, scores, batch, mp, sp);
    hipLaunchKernelGGL(stats_merge, dim3(64), dim3(256), 0, stream, mp, sp, mm, di);
    hipLaunchKernelGGL(attend, dim3(64, 8, 4), dim3(256), 0, stream, scores, vh, batch, mm, di, att4);
    // graph_repr = (sum_c att4) @ Wo^T + bo   [2048,256]
    hipLaunchKernelGGL(gemm_wo, dim3(4, 32), dim3(256), 0, stream, att4, Wo, bo, gr);
    // h1_pre split-K over K=8192, 64-way split (256 blocks)
    hipLaunchKernelGGL(gemm_w1_splitk, dim3(4, 64), dim3(256), 0, stream, gr, W1, part);
    hipLaunchKernelGGL(silu_reduce, dim3(64), dim3(256), 0, stream, part, b1, h1);
    // out = h1 @ W2^T + b2   [64,256]
    hipLaunchKernelGGL(gemm_w2, dim3(64), dim3(256), 0, stream, h1, W2, b2, out);
}